// Round 16
// baseline (169.668 us; speedup 1.0000x reference)
//
#include <hip/hip_runtime.h>
#include <math.h>

// GlobalLocalAttention — round 15: DE-fuse la_qkv (co-compiled VGPR coupling
// cost > overlap gain). qkv = standalone gemm_bt (18.4KB LDS, 2-pass
// epilogue); local_attn standalone (2D tiles + XCD swizzle, own VGPR budget).
//
// Pipeline:
//  1. prep:    {x -> XT bf16}  ∪  {weights -> W7 bf16}
//  2. gemm_bt(W7[0:1024])    -> GA bf16 [b][NP][1024]
//  3. gemm_bt(W7[1024:1792]) -> GB bf16 [b][NP][768]
//  4. local_attn3(GA)        -> localB bf16
//  5. window_attn_mfma(GB)   -> attnB bf16 (aliases XT, dead)
//  6. pool_dw8               -> dwB fp32 (over dead GA)
//  7. xpose(dwB)             -> XT2 bf16
//  8. gemm_cf32(W7[1792:2048], XT2) -> d_out

namespace {

constexpr int NP = 96 * 96;   // 9216
constexpr int C  = 256;

typedef __bf16 bf16x8 __attribute__((ext_vector_type(8)));
typedef __bf16 bf16x4 __attribute__((ext_vector_type(4)));
typedef float  f32x4  __attribute__((ext_vector_type(4)));
typedef float  f32x16 __attribute__((ext_vector_type(16)));

__device__ __forceinline__ unsigned short f2bf_rne(float f) {
  unsigned u = __float_as_uint(f);
  u += 0x7FFFu + ((u >> 16) & 1u);
  return (unsigned short)(u >> 16);
}
__device__ __forceinline__ __bf16 f2bf16(float f) {
  unsigned short s = f2bf_rne(f);
  return *(__bf16*)&s;
}
__device__ __forceinline__ float bf2f(unsigned short s) {
  unsigned u = (unsigned)s << 16;
  return __uint_as_float(u);
}
__device__ __forceinline__ float4 bf4_to_f4(const unsigned short* p) {
  bf16x4 v = *(const bf16x4*)p;
  float4 r;
  r.x = (float)v[0]; r.y = (float)v[1]; r.z = (float)v[2]; r.w = (float)v[3];
  return r;
}

// ---------------- merged prep: weight cvt (blocks 0..2047) + x transpose ----
__global__ __launch_bounds__(256) void prep(
    const float* __restrict__ x,
    const float* __restrict__ l2, const float* __restrict__ q,
    const float* __restrict__ k,  const float* __restrict__ v,
    const float* __restrict__ qkv, const float* __restrict__ pw,
    unsigned short* __restrict__ XT, unsigned short* __restrict__ W7)
{
  __shared__ float tile[64][65];
  const int bx = blockIdx.x;
  const int t = threadIdx.x;
  if (bx < 2048) {
    const int row = bx;
    const float* src; int r;
    if      (row <  256) { src = l2;  r = row; }
    else if (row <  512) { src = q;   r = row - 256; }
    else if (row <  768) { src = k;   r = row - 512; }
    else if (row < 1024) { src = v;   r = row - 768; }
    else if (row < 1792) { src = qkv; r = row - 1024; }
    else                 { src = pw;  r = row - 1792; }
    W7[row * 256 + t] = f2bf_rne(src[r * 256 + t]);
    return;
  }
  const int xb = bx - 2048;
  const int p0 = (xb % 144) * 64;
  const int c0 = ((xb / 144) % 4) * 64;
  const int b  = xb / 576;
  const float* xb_p = x + (long)b * C * NP;
#pragma unroll
  for (int i = 0; i < 4; ++i) {
    int s = i * 256 + t;
    int c = s >> 4, p4 = s & 15;
    float4 vv = *(const float4*)&xb_p[(long)(c0 + c) * NP + p0 + p4 * 4];
    tile[c][p4 * 4 + 0] = vv.x;
    tile[c][p4 * 4 + 1] = vv.y;
    tile[c][p4 * 4 + 2] = vv.z;
    tile[c][p4 * 4 + 3] = vv.w;
  }
  __syncthreads();
  unsigned short* XTb = XT + (long)b * NP * 256;
#pragma unroll
  for (int i = 0; i < 2; ++i) {
    int s = i * 256 + t;
    int p = s >> 3, c8 = s & 7;
    unsigned short u[8];
#pragma unroll
    for (int e = 0; e < 8; ++e) u[e] = f2bf_rne(tile[c8 * 8 + e][p]);
    *(uint4*)&XTb[(long)(p0 + p) * 256 + c0 + c8 * 8] = *(const uint4*)u;
  }
}

// ---------------- transpose: fp32 [c][pix] -> bf16 [pix][c] (dwB -> XT2) ---
__global__ __launch_bounds__(256) void xpose(
    const float* __restrict__ x, unsigned short* __restrict__ XT)
{
  __shared__ float tile[64][65];
  const int t = threadIdx.x;
  const int p0 = blockIdx.x * 64, c0 = blockIdx.y * 64, b = blockIdx.z;
  const float* xb = x + (long)b * C * NP;
#pragma unroll
  for (int i = 0; i < 4; ++i) {
    int s = i * 256 + t;
    int c = s >> 4, p4 = s & 15;
    float4 v = *(const float4*)&xb[(long)(c0 + c) * NP + p0 + p4 * 4];
    tile[c][p4 * 4 + 0] = v.x;
    tile[c][p4 * 4 + 1] = v.y;
    tile[c][p4 * 4 + 2] = v.z;
    tile[c][p4 * 4 + 3] = v.w;
  }
  __syncthreads();
  unsigned short* XTb = XT + (long)b * NP * 256;
#pragma unroll
  for (int i = 0; i < 2; ++i) {
    int s = i * 256 + t;
    int p = s >> 3, c8 = s & 7;
    unsigned short u[8];
#pragma unroll
    for (int e = 0; e < 8; ++e) u[e] = f2bf_rne(tile[c8 * 8 + e][p]);
    *(uint4*)&XTb[(long)(p0 + p) * 256 + c0 + c8 * 8] = *(const uint4*)u;
  }
}

// ---------------- gemm tile body (gll staging; 2-pass within-wave epilogue) -
__device__ __forceinline__ void gemm_bt_body(
    unsigned short* smemS,
    const unsigned short* __restrict__ W, const unsigned short* __restrict__ XTb,
    unsigned short* __restrict__ Ob, int Mstride, int m0, int n0)
{
  unsigned short* As = smemS;            // [128][32] linear
  unsigned short* Bs = smemS + 4096;     // [128][32] linear

  const int t = threadIdx.x;
  const int lane = t & 63, wid = t >> 6;
  const int wm = wid >> 1, wn = wid & 1;
  const int l15 = lane & 15, l4 = lane >> 4;
  const int crow = lane >> 2;
  const int ccol = (lane & 3) * 8;

  f32x4 acc[4][4];
#pragma unroll
  for (int i = 0; i < 4; ++i)
#pragma unroll
    for (int j = 0; j < 4; ++j) acc[i][j] = (f32x4){0.f, 0.f, 0.f, 0.f};

  for (int k0 = 0; k0 < 256; k0 += 32) {
#pragma unroll
    for (int i = 0; i < 4; ++i) {
      const int ch = wid * 4 + i;
      if (ch < 8) {
        const int row = ch * 16 + crow;
        __builtin_amdgcn_global_load_lds(
            (const __attribute__((address_space(1))) unsigned int*)
                &W[(long)(m0 + row) * 256 + k0 + ccol],
            (__attribute__((address_space(3))) unsigned int*)&As[ch * 512],
            16, 0, 0);
      } else {
        const int row = (ch - 8) * 16 + crow;
        __builtin_amdgcn_global_load_lds(
            (const __attribute__((address_space(1))) unsigned int*)
                &XTb[(long)(n0 + row) * 256 + k0 + ccol],
            (__attribute__((address_space(3))) unsigned int*)&Bs[(ch - 8) * 512],
            16, 0, 0);
      }
    }
    __syncthreads();

    bf16x8 af[4], bb[4];
#pragma unroll
    for (int mf = 0; mf < 4; ++mf)
      af[mf] = *(const bf16x8*)&As[(wm * 64 + mf * 16 + l15) * 32 + l4 * 8];
#pragma unroll
    for (int nf = 0; nf < 4; ++nf)
      bb[nf] = *(const bf16x8*)&Bs[(wn * 64 + nf * 16 + l15) * 32 + l4 * 8];
#pragma unroll
    for (int mf = 0; mf < 4; ++mf)
#pragma unroll
      for (int nf = 0; nf < 4; ++nf)
        acc[mf][nf] = __builtin_amdgcn_mfma_f32_16x16x32_bf16(
            af[mf], bb[nf], acc[mf][nf], 0, 0, 0);
    __syncthreads();
  }

  // Epilogue: per-wave 32x72 region; within-wave only, no barriers.
  unsigned short* trw = smemS + wid * 2304;      // 32 * 72 shorts
  const int lp = lane >> 1;                      // local pixel 0..31
  const int cbase = (lane & 1) * 4;              // 4 chunks of 16B each
#pragma unroll
  for (int pass = 0; pass < 2; ++pass) {
#pragma unroll
    for (int nfh = 0; nfh < 2; ++nfh) {
      const int nf = pass * 2 + nfh;
#pragma unroll
      for (int mf = 0; mf < 4; ++mf) {
        unsigned u0 = (unsigned)f2bf_rne(acc[mf][nf][0]) |
                      ((unsigned)f2bf_rne(acc[mf][nf][1]) << 16);
        unsigned u1 = (unsigned)f2bf_rne(acc[mf][nf][2]) |
                      ((unsigned)f2bf_rne(acc[mf][nf][3]) << 16);
        uint2 uu; uu.x = u0; uu.y = u1;
        *(uint2*)&trw[(nfh * 16 + l15) * 72 + mf * 16 + l4 * 4] = uu;
      }
    }
    const long pix = n0 + wn * 64 + pass * 32 + lp;
    const long rowbase = pix * Mstride + m0 + wm * 64;
#pragma unroll
    for (int cc = 0; cc < 4; ++cc)
      *(uint4*)&Ob[rowbase + (cbase + cc) * 8] =
          *(const uint4*)&trw[lp * 72 + (cbase + cc) * 8];
  }
}

// ---------------- GEMM kernel (A-phase and qkv both use this) ---------------
__global__ __launch_bounds__(256) void gemm_bt(
    const unsigned short* __restrict__ W, const unsigned short* __restrict__ XT,
    unsigned short* __restrict__ O, int Mstride)
{
  __shared__ __align__(16) unsigned short smemS[9216];   // 18,432 B
  gemm_bt_body(smemS, W, XT + (long)blockIdx.z * NP * 256,
               O + (long)blockIdx.z * NP * Mstride, Mstride,
               blockIdx.y * 128, blockIdx.x * 128);
}

// ---------------- local_attn standalone: 2D 8x4 tile + XCD swizzle ----------
__global__ __launch_bounds__(256) void local_attn3(
    const unsigned short* __restrict__ GA,
    const float* __restrict__ rel_x, const float* __restrict__ rel_y,
    const float* __restrict__ bn2_g, const float* __restrict__ bn2_b,
    const float* __restrict__ bn2_m, const float* __restrict__ bn2_v,
    const float* __restrict__ l1_bias, unsigned short* __restrict__ localO)
{
  __shared__ float red[8][32][13];
  __shared__ float srel[256 * 3];
  __shared__ float sS[256], sO[256], sBias[256];

  const int orig = blockIdx.x;          // 0..287
  const int b = blockIdx.y;
  // XCD-aware bijective swizzle (288 % 8 == 0)
  const int tile = (orig & 7) * 36 + (orig >> 3);

  const int t = threadIdx.x;
  const int px = t & 31, ch = t >> 5;
  const int ty = tile / 24, tx = tile % 24;
  const int h = ty * 8 + (px >> 2), w = tx * 4 + (px & 3);
  const int p = h * 96 + w;
  const unsigned short* Gb = GA + (long)b * NP * 1024;

  if (t < 128) {
    srel[t * 3 + 0] = rel_x[t * 3 + 0];
    srel[t * 3 + 1] = rel_x[t * 3 + 1];
    srel[t * 3 + 2] = rel_x[t * 3 + 2];
  } else {
    int r = t - 128;
    srel[t * 3 + 0] = rel_y[r * 3 + 0];
    srel[t * 3 + 1] = rel_y[r * 3 + 1];
    srel[t * 3 + 2] = rel_y[r * 3 + 2];
  }
  {
    float s = bn2_g[t] * rsqrtf(bn2_v[t] + 1e-5f);
    sS[t] = s;
    sO[t] = bn2_b[t] - bn2_m[t] * s;
    sBias[t] = l1_bias[t];
  }

  int nof[9];
  float msk[9];
#pragma unroll
  for (int ky = 0; ky < 3; ++ky)
#pragma unroll
    for (int kx = 0; kx < 3; ++kx) {
      int j = ky * 3 + kx, hn = h + ky - 1, wn = w + kx - 1;
      bool v = (hn >= 0 && hn < 96 && wn >= 0 && wn < 96);
      nof[j] = v ? hn * 96 + wn : p;
      msk[j] = v ? 1.f : 0.f;
    }
  __syncthreads();

  float lg[9] = {0, 0, 0, 0, 0, 0, 0, 0, 0};
  float rq[3] = {0, 0, 0};
  const int c0 = ch * 32;
#pragma unroll
  for (int i = 0; i < 4; ++i) {
    const int c = c0 + i * 8;
    bf16x8 q8 = *(const bf16x8*)&Gb[(long)p * 1024 + 256 + c];
    float qv[8];
#pragma unroll
    for (int e = 0; e < 8; ++e) qv[e] = (float)q8[e];
#pragma unroll
    for (int j = 0; j < 9; ++j) {
      bf16x8 k8 = *(const bf16x8*)&Gb[(long)nof[j] * 1024 + 512 + c];
#pragma unroll
      for (int e = 0; e < 8; ++e) lg[j] += qv[e] * (float)k8[e];
    }
#pragma unroll
    for (int e = 0; e < 8; ++e) {
      const float* sr = &srel[(c + e) * 3];
      rq[0] += qv[e] * sr[0];
      rq[1] += qv[e] * sr[1];
      rq[2] += qv[e] * sr[2];
    }
  }
#pragma unroll
  for (int j = 0; j < 9; ++j) red[ch][px][j] = lg[j] * msk[j];
#pragma unroll
  for (int l = 0; l < 3; ++l) red[ch][px][9 + l] = rq[l];
  __syncthreads();

  float a[9];
  float mx = -1e30f;
#pragma unroll
  for (int j = 0; j < 9; ++j) {
    float v = 0.f;
#pragma unroll
    for (int u = 0; u < 8; ++u) v += red[u][px][j];
    float qxl = red[0][px][9 + j % 3] + red[1][px][9 + j % 3] +
                red[2][px][9 + j % 3] + red[3][px][9 + j % 3];
    float qyk = red[4][px][9 + j / 3] + red[5][px][9 + j / 3] +
                red[6][px][9 + j / 3] + red[7][px][9 + j / 3];
    a[j] = v + qxl + qyk;
    mx = fmaxf(mx, a[j]);
  }
  float sum = 0.f;
#pragma unroll
  for (int j = 0; j < 9; ++j) { a[j] = __expf(a[j] - mx); sum += a[j]; }
  const float inv = 1.f / sum;
  float am[9];
#pragma unroll
  for (int j = 0; j < 9; ++j) am[j] = a[j] * inv * msk[j];

#pragma unroll
  for (int i = 0; i < 4; ++i) {
    const int c = c0 + i * 8;
    bf16x8 l28 = *(const bf16x8*)&Gb[(long)p * 1024 + 0 + c];
    float o8[8] = {0, 0, 0, 0, 0, 0, 0, 0};
#pragma unroll
    for (int j = 0; j < 9; ++j) {
      bf16x8 v8 = *(const bf16x8*)&Gb[(long)nof[j] * 1024 + 768 + c];
#pragma unroll
      for (int e = 0; e < 8; ++e) o8[e] += am[j] * (float)v8[e];
    }
#pragma unroll
    for (int e = 0; e < 8; ++e) {
      const int cg = c + e;
      localO[((long)b * C + cg) * NP + p] = f2bf_rne(
          (float)l28[e] * sS[cg] + sO[cg] + o8[e] + sBias[cg]);
    }
  }
}

// ---------------- bf16 GEMM, fp32 channel-major out, 64x128 tile (pw) ------
__global__ __launch_bounds__(256) void gemm_cf32(
    const unsigned short* __restrict__ W, const unsigned short* __restrict__ XT,
    float* __restrict__ Co)
{
  __shared__ unsigned short As[64][40];
  __shared__ unsigned short Bs[128][40];

  const int t = threadIdx.x;
  const int lane = t & 63, wid = t >> 6;
  const int wm = wid >> 1, wn = wid & 1;
  const int l15 = lane & 15, l4 = lane >> 4;
  const int n0 = blockIdx.x * 128, m0 = blockIdx.y * 64;
  const unsigned short* XTb = XT + (long)blockIdx.z * NP * 256;
  float* Cb = Co + (long)blockIdx.z * C * NP;

  f32x4 acc[2][4];
#pragma unroll
  for (int i = 0; i < 2; ++i)
#pragma unroll
    for (int j = 0; j < 4; ++j) acc[i][j] = (f32x4){0.f, 0.f, 0.f, 0.f};

  for (int k0 = 0; k0 < 256; k0 += 32) {
    {
      int r = t >> 2, kc = t & 3;
      *(uint4*)&As[r][kc * 8] =
          *(const uint4*)&W[(long)(m0 + r) * 256 + k0 + kc * 8];
    }
#pragma unroll
    for (int i = 0; i < 2; ++i) {
      int s = i * 256 + t, r = s >> 2, kc = s & 3;
      *(uint4*)&Bs[r][kc * 8] =
          *(const uint4*)&XTb[(long)(n0 + r) * 256 + k0 + kc * 8];
    }
    __syncthreads();

    bf16x8 af[2], bb[4];
#pragma unroll
    for (int mf = 0; mf < 2; ++mf)
      af[mf] = *(const bf16x8*)&As[wm * 32 + mf * 16 + l15][l4 * 8];
#pragma unroll
    for (int nf = 0; nf < 4; ++nf)
      bb[nf] = *(const bf16x8*)&Bs[wn * 64 + nf * 16 + l15][l4 * 8];
#pragma unroll
    for (int mf = 0; mf < 2; ++mf)
#pragma unroll
      for (int nf = 0; nf < 4; ++nf)
        acc[mf][nf] = __builtin_amdgcn_mfma_f32_16x16x32_bf16(
            af[mf], bb[nf], acc[mf][nf], 0, 0, 0);
    __syncthreads();
  }

#pragma unroll
  for (int mf = 0; mf < 2; ++mf)
#pragma unroll
    for (int r = 0; r < 4; ++r) {
      int row = m0 + wm * 32 + mf * 16 + l4 * 4 + r;
#pragma unroll
      for (int nf = 0; nf < 4; ++nf) {
        int col = n0 + wn * 64 + nf * 16 + l15;
        Cb[(long)row * NP + col] = acc[mf][nf][r];
      }
    }
}

// ---------------- 8x8 window attention via MFMA -> bf16 --------------------
__global__ __launch_bounds__(64) void window_attn_mfma(
    const unsigned short* __restrict__ QKV,
    const float* __restrict__ rel_table, unsigned short* __restrict__ attnO)
{
  const int win = blockIdx.x, hd = blockIdx.y, b = blockIdx.z;
  const int wy = win / 12, wx = win % 12;
  const int lane = threadIdx.x;
  const int l15 = lane & 15, hi4 = lane >> 4;
  const int l31 = lane & 31, hi2 = lane >> 5;

  __shared__ float srpb[225];
  __shared__ __bf16 P[64][72];

  for (int i = lane; i < 225; i += 64) srpb[i] = rel_table[i * 16 + hd];

  const __bf16* base = (const __bf16*)QKV + (long)b * 9216 * 768;
  const int pixbase = (wy * 8) * 96 + wx * 8;

#define WPIX(i) (pixbase + ((i) >> 3) * 96 + ((i) & 7))

  bf16x8 kf[2], qf[2];
#pragma unroll
  for (int kt = 0; kt < 2; ++kt)
    kf[kt] = *(const bf16x8*)&base[(long)WPIX(32 * kt + l31) * 768 + 256 +
                                   hd * 16 + hi2 * 8];
#pragma unroll
  for (int qt = 0; qt < 2; ++qt)
    qf[qt] = *(const bf16x8*)&base[(long)WPIX(32 * qt + l31) * 768 +
                                   hd * 16 + hi2 * 8];

  bf16x8 vf[2];
#pragma unroll
  for (int kc = 0; kc < 2; ++kc)
#pragma unroll
    for (int j = 0; j < 8; ++j)
      vf[kc][j] = base[(long)WPIX(32 * kc + 8 * hi4 + j) * 768 + 512 +
                       hd * 16 + l15];

  f32x16 S[2][2];
#pragma unroll
  for (int kt = 0; kt < 2; ++kt)
#pragma unroll
    for (int qt = 0; qt < 2; ++qt)
#pragma unroll
      for (int r = 0; r < 16; ++r) S[kt][qt][r] = 0.f;

#pragma unroll
  for (int kt = 0; kt < 2; ++kt)
#pragma unroll
    for (int qt = 0; qt < 2; ++qt)
      S[kt][qt] = __builtin_amdgcn_mfma_f32_32x32x16_bf16(
          kf[kt], qf[qt], S[kt][qt], 0, 0, 0);

  __syncthreads();

  float mx[2] = {-1e30f, -1e30f};
#pragma unroll
  for (int kt = 0; kt < 2; ++kt)
#pragma unroll
    for (int r = 0; r < 16; ++r) {
      const int key = 32 * kt + (r & 3) + 8 * (r >> 2) + 4 * hi2;
      const int ky = key >> 3, kx = key & 7;
#pragma unroll
      for (int qt = 0; qt < 2; ++qt) {
        const int q = 32 * qt + l31;
        const int qy = q >> 3, qx = q & 7;
        float s = S[kt][qt][r] * 0.25f + srpb[(qy - ky + 7) * 15 + (qx - kx + 7)];
        S[kt][qt][r] = s;
        mx[qt] = fmaxf(mx[qt], s);
      }
    }
#pragma unroll
  for (int qt = 0; qt < 2; ++qt)
    mx[qt] = fmaxf(mx[qt], __shfl_xor(mx[qt], 32));

  float sum[2] = {0.f, 0.f};
#pragma unroll
  for (int kt = 0; kt < 2; ++kt)
#pragma unroll
    for (int qt = 0; qt < 2; ++qt)
#pragma unroll
      for (int r = 0; r < 16; ++r) {
        float e = __expf(S[kt][qt][r] - mx[qt]);
        S[kt][qt][r] = e;
        sum[qt] += e;
      }
#pragma unroll
  for (int qt = 0; qt < 2; ++qt) sum[qt] += __shfl_xor(sum[qt], 32);
  const float inv0 = 1.f / sum[0], inv1 = 1.f / sum[1];

#pragma unroll
  for (int qt = 0; qt < 2; ++qt) {
    const float inv = qt ? inv1 : inv0;
#pragma unroll
    for (int kt = 0; kt < 2; ++kt)
#pragma unroll
      for (int rq = 0; rq < 4; ++rq) {
        bf16x4 pk;
#pragma unroll
        for (int j = 0; j < 4; ++j) pk[j] = f2bf16(S[kt][qt][rq * 4 + j] * inv);
        *(bf16x4*)&P[32 * qt + l31][32 * kt + 8 * rq + 4 * hi2] = pk;
      }
  }
  __syncthreads();

  f32x4 o[4];
#pragma unroll
  for (int qt4 = 0; qt4 < 4; ++qt4) o[qt4] = (f32x4){0.f, 0.f, 0.f, 0.f};
#pragma unroll
  for (int kc = 0; kc < 2; ++kc)
#pragma unroll
    for (int qt4 = 0; qt4 < 4; ++qt4) {
      bf16x8 pf = *(const bf16x8*)&P[16 * qt4 + l15][32 * kc + 8 * hi4];
      o[qt4] = __builtin_amdgcn_mfma_f32_16x16x32_bf16(vf[kc], pf, o[qt4], 0, 0, 0);
    }

#pragma unroll
  for (int qt4 = 0; qt4 < 4; ++qt4)
#pragma unroll
    for (int r = 0; r < 4; ++r) {
      const int q = 16 * qt4 + l15;
      attnO[((long)b * C + hd * 16 + 4 * hi4 + r) * NP + WPIX(q)] =
          f2bf_rne(o[qt4][r]);
    }
#undef WPIX
}

// ---------------- fused pools + combine + dw conv + BN (conflict-free f4) --
__global__ __launch_bounds__(128) void pool_dw8(
    const unsigned short* __restrict__ attn,
    const unsigned short* __restrict__ localO,
    const float* __restrict__ dww,
    const float* __restrict__ bnp_g, const float* __restrict__ bnp_b,
    const float* __restrict__ bnp_m, const float* __restrict__ bnp_v,
    float* __restrict__ dst)
{
  const int r0 = blockIdx.x * 12;
  const int c = blockIdx.y, b = blockIdx.z;
  const int t = threadIdx.x;

  __shared__ float img[26 * 116];
  __shared__ float img2[19 * 108];

  const unsigned short* A = attn + ((long)b * C + c) * NP;
  const unsigned short* L = localO + ((long)b * C + c) * NP;

  for (int idx = t; idx < 26 * 28; idx += 128) {
    const int j = idx / 28, k = idx % 28;
    const int R = r0 - 6 + j;
    const bool rv = (R >= 0 && R <= 96);
    const int Rc = (R == 96) ? 94 : (rv ? R : 0);
    const int s0 = 4 * k - 8;
    float4 v = {-1e30f, -1e30f, -1e30f, -1e30f};
    if (rv && s0 >= 0 && s0 <= 92) v = bf4_to_f4(&A[Rc * 96 + s0]);
    else if (rv && s0 == 96) v.x = bf2f(A[Rc * 96 + 94]);
    *(float4*)&img[j * 116 + 4 * k] = v;
  }
  for (int idx = t; idx < 19 * 27; idx += 128) {
    const int j2 = idx / 27, g = idx % 27;
    const int R2 = r0 - 3 + j2;
    const bool rv = (R2 >= 0 && R2 <= 96);
    const int R2c = (R2 == 96) ? 94 : (rv ? R2 : 0);
    const int w0 = 4 * g - 4;
    float4 v = {0.f, 0.f, 0.f, 0.f};
    if (rv) {
      if (w0 >= 0 && w0 <= 92) v = bf4_to_f4(&L[R2c * 96 + w0]);
      else if (w0 == 96) v.x = bf2f(L[R2c * 96 + 94]);
    }
    *(float4*)&img2[j2 * 108 + 4 * g] = v;
  }
  float wr[64];
#pragma unroll
  for (int i = 0; i < 64; ++i) wr[i] = dww[c * 64 + i];
  const float scl = bnp_g[c] * rsqrtf(bnp_v[c] + 1e-5f);
  const float off = bnp_b[c] - bnp_m[c] * scl;
  __syncthreads();

  const int j2lo = (r0 == 0) ? 3 : 0;
  const int j2hi = (r0 == 84) ? 14 : 18;
  if (t < 120) {
    const int blk = t / 24, G = t % 24;
    const int j2b = j2lo + blk * 4;
    if (j2b <= j2hi) {
      float4 hc[11];
#pragma unroll
      for (int ii = 0; ii < 11; ++ii) {
        int rr = j2b + ii;
        rr = (rr > 25) ? 25 : rr;
        hc[ii] = *(const float4*)&img[rr * 116 + 4 * G + 8];
      }
#pragma unroll
      for (int r = 0; r < 4; ++r) {
        const int j2 = j2b + r;
        if (j2 > j2hi) break;
        float mph[4] = {-1e30f, -1e30f, -1e30f, -1e30f};
        float aph[4] = {0.f, 0.f, 0.f, 0.f};
#pragma unroll
        for (int ii = 0; ii < 8; ++ii) {
          const float h4[4] = {hc[r + ii].x, hc[r + ii].y, hc[r + ii].z,
                               hc[r + ii].w};
#pragma unroll
          for (int d = 0; d < 4; ++d) {
            mph[d] = fmaxf(mph[d], h4[d]);
            aph[d] += (h4[d] > -1e29f) ? h4[d] : 0.f;
          }
        }
        float rw[12];
        {
          const float* row = &img[(j2 + 3) * 116 + 4 * G + 4];
          float4 a0 = *(const float4*)&row[0];
          float4 a1 = *(const float4*)&row[4];
          float4 a2 = *(const float4*)&row[8];
          rw[0] = a0.x; rw[1] = a0.y; rw[2] = a0.z; rw[3] = a0.w;
          rw[4] = a1.x; rw[5] = a1.y; rw[6] = a1.z; rw[7] = a1.w;
          rw[8] = a2.x; rw[9] = a2.y; rw[10] = a2.z; rw[11] = a2.w;
        }
        float4 lv = *(const float4*)&img2[j2 * 108 + 4 * G + 4];
        const float l4[4] = {lv.x, lv.y, lv.z, lv.w};
        float o4[4];
#pragma unroll
        for (int d = 0; d < 4; ++d) {
          float mpw = -1e30f, apw = 0.f;
#pragma unroll
          for (int ii = 0; ii < 8; ++ii) {
            const float wv = rw[d + 1 + ii];
            mpw = fmaxf(mpw, wv);
            apw += (wv > -1e29f) ? wv : 0.f;
          }
          o4[d] = mph[d] + mpw + (aph[d] + apw) * 0.125f + l4[d];
        }
        float4 out;
        out.x = o4[0]; out.y = o4[1]; out.z = o4[2]; out.w = o4[3];
        *(float4*)&img2[j2 * 108 + 4 * G + 4] = out;
        if (G == 23) img2[j2 * 108 + 100] = o4[2];
        if (r0 == 84 && j2 == 13) {
          *(float4*)&img2[15 * 108 + 4 * G + 4] = out;
          if (G == 23) img2[15 * 108 + 100] = o4[2];
        }
      }
    }
  }
  __syncthreads();

  if (t < 72) {
    const int cb = t / 24, ocg = t % 24;
    const int hh0 = cb * 4;
    float acc[4][4];
#pragma unroll
    for (int o = 0; o < 4; ++o)
#pragma unroll
      for (int d = 0; d < 4; ++d) acc[o][d] = 0.f;
#pragma unroll
    for (int i = 0; i < 11; ++i) {
      const float* row = &img2[(hh0 + i) * 108 + 4 * ocg];
      float w12[12];
      {
        float4 a0 = *(const float4*)&row[0];
        float4 a1 = *(const float4*)&row[4];
        float4 a2 = *(const float4*)&row[8];
        w12[0] = a0.x; w12[1] = a0.y; w12[2] = a0.z; w12[3] = a0.w;
        w12[4] = a1.x; w12[5] = a1.y; w12[6] = a1.z; w12[7] = a1.w;
        w12[8] = a2.x; w12[9] = a2.y; w12[10] = a2.z; w12[11] = a2.w;
      }
#pragma unroll
      for (int o = 0; o < 4; ++o) {
        if (o > i || i - o > 7) continue;
        const int ir = i - o;
#pragma unroll
        for (int d = 0; d < 4; ++d)
#pragma unroll
          for (int jj = 0; jj < 8; ++jj)
            acc[o][d] = fmaf(wr[ir * 8 + jj], w12[d + 1 + jj], acc[o][d]);
      }
    }
#pragma unroll
    for (int o = 0; o < 4; ++o) {
      float4 s;
      s.x = acc[o][0] * scl + off;
      s.y = acc[o][1] * scl + off;
      s.z = acc[o][2] * scl + off;
      s.w = acc[o][3] * scl + off;
      *(float4*)&dst[((long)b * C + c) * NP + (r0 + hh0 + o) * 96 + 4 * ocg] = s;
    }
  }
}

}  // namespace

extern "C" void kernel_launch(void* const* d_in, const int* in_sizes, int n_in,
                              void* d_out, int out_size, void* d_ws, size_t ws_size,
                              hipStream_t stream) {
  const float* x         = (const float*)d_in[0];
  const float* qkv_w     = (const float*)d_in[1];
  const float* l2_w      = (const float*)d_in[2];
  const float* bn2_g     = (const float*)d_in[3];
  const float* bn2_b     = (const float*)d_in[4];
  const float* bn2_m     = (const float*)d_in[5];
  const float* bn2_v     = (const float*)d_in[6];
  const float* wq        = (const float*)d_in[7];
  const float* wk        = (const float*)d_in[8];
  const float* wv        = (const float*)d_in[9];
  const float* rel_x     = (const float*)d_in[10];
  const float* rel_y     = (const float*)d_in[11];
  const float* l1_bias   = (const float*)d_in[12];
  const float* rel_table = (const float*)d_in[13];
  const float* dw_w      = (const float*)d_in[14];
  const float* bnp_g     = (const float*)d_in[15];
  const float* bnp_b     = (const float*)d_in[16];
  const float* bnp_m     = (const float*)d_in[17];
  const float* bnp_v     = (const float*)d_in[18];
  const float* pw_w      = (const float*)d_in[19];
  float* out = (float*)d_out;
  float* ws  = (float*)d_ws;

  unsigned short* GA     = (unsigned short*)ws;                      // [0,9.44M)
  unsigned short* GB     = (unsigned short*)(ws + 9437184);          // 7.08M
  unsigned short* localB = (unsigned short*)(ws + 16515072);         // 2.36M
  unsigned short* W7     = (unsigned short*)(ws + 18874368);         // 0.26M
  unsigned short* XT     = (unsigned short*)(ws + 19136512);         // 2.36M
  unsigned short* attnB  = (unsigned short*)(ws + 19136512);         // alias XT
  float*          dwB    = ws;                                       // over GA
  unsigned short* XT2    = (unsigned short*)(ws + 4718592);          // over GA

  // 1. prep: weights -> W7 (blocks 0..2047) + x -> XT (blocks 2048..3199)
  prep<<<dim3(3200), 256, 0, stream>>>(x, l2_w, wq, wk, wv, qkv_w, pw_w,
                                       XT, W7);

  // 2. [l2|qL|kL|vL] -> GA bf16 [pix][1024]
  gemm_bt<<<dim3(72, 8, 2), 256, 0, stream>>>(W7, XT, GA, 1024);

  // 3. qkv -> GB bf16 [pix][768]
  gemm_bt<<<dim3(72, 6, 2), 256, 0, stream>>>(W7 + 1024 * 256, XT, GB, 768);

  // 4. neighborhood attention + BN + bias -> localB
  local_attn3<<<dim3(288, 2), 256, 0, stream>>>(GA, rel_x, rel_y, bn2_g,
                                                bn2_b, bn2_m, bn2_v, l1_bias,
                                                localB);

  // 5. window attention (MFMA) -> attnB (over dead XT)
  window_attn_mfma<<<dim3(144, 16, 2), 64, 0, stream>>>(GB, rel_table, attnB);

  // 6. pools + combine + depthwise conv + BN -> dwB (over dead GA)
  pool_dw8<<<dim3(8, 256, 2), 128, 0, stream>>>(attnB, localB, dw_w, bnp_g,
                                                bnp_b, bnp_m, bnp_v, dwB);

  // 7. dwB -> XT2 bf16 [pix][256]
  xpose<<<dim3(144, 4, 2), 256, 0, stream>>>(dwB, XT2);

  // 8. pointwise GEMM -> out (fp32 channel-major, 64x128 tiles)
  gemm_cf32<<<dim3(72, 4, 2), 256, 0, stream>>>(W7 + 1792 * 256, XT2, out);
}

// Round 17
// 166.387 us; speedup vs baseline: 1.0197x; 1.0197x over previous
//
#include <hip/hip_runtime.h>
#include <math.h>

// GlobalLocalAttention — round 16: revert to R14 (fused la_qkv + interleave,
// best measured) + bf16 dwB (halves pool_dw->xpose round trip; numerically
// identical since XT2 was bf16-rounded anyway).
//
// Pipeline:
//  1. prep:    {x -> XT bf16}  ∪  {weights -> W7 bf16}
//  2. gemm_bt(W7[0:1024])    -> GA bf16 [b][NP][1024]
//  3. la_qkv:  {gemm qkv -> GB}  ∥  {local_attn(GA) -> localB}  (3:2 interleave)
//  4. window_attn_mfma(GB)   -> attnB bf16 (aliases XT, dead)
//  5. pool_dw8               -> dwB bf16 (over dead GA)
//  6. xpose_bf(dwB)          -> XT2 bf16
//  7. gemm_cf32(W7[1792:2048], XT2) -> d_out

namespace {

constexpr int NP = 96 * 96;   // 9216
constexpr int C  = 256;

typedef __bf16 bf16x8 __attribute__((ext_vector_type(8)));
typedef __bf16 bf16x4 __attribute__((ext_vector_type(4)));
typedef float  f32x4  __attribute__((ext_vector_type(4)));
typedef float  f32x16 __attribute__((ext_vector_type(16)));

__device__ __forceinline__ unsigned short f2bf_rne(float f) {
  unsigned u = __float_as_uint(f);
  u += 0x7FFFu + ((u >> 16) & 1u);
  return (unsigned short)(u >> 16);
}
__device__ __forceinline__ __bf16 f2bf16(float f) {
  unsigned short s = f2bf_rne(f);
  return *(__bf16*)&s;
}
__device__ __forceinline__ float bf2f(unsigned short s) {
  unsigned u = (unsigned)s << 16;
  return __uint_as_float(u);
}
__device__ __forceinline__ float4 bf4_to_f4(const unsigned short* p) {
  bf16x4 v = *(const bf16x4*)p;
  float4 r;
  r.x = (float)v[0]; r.y = (float)v[1]; r.z = (float)v[2]; r.w = (float)v[3];
  return r;
}

// ---------------- merged prep: weight cvt (blocks 0..2047) + x transpose ----
__global__ __launch_bounds__(256) void prep(
    const float* __restrict__ x,
    const float* __restrict__ l2, const float* __restrict__ q,
    const float* __restrict__ k,  const float* __restrict__ v,
    const float* __restrict__ qkv, const float* __restrict__ pw,
    unsigned short* __restrict__ XT, unsigned short* __restrict__ W7)
{
  __shared__ float tile[64][65];
  const int bx = blockIdx.x;
  const int t = threadIdx.x;
  if (bx < 2048) {
    const int row = bx;
    const float* src; int r;
    if      (row <  256) { src = l2;  r = row; }
    else if (row <  512) { src = q;   r = row - 256; }
    else if (row <  768) { src = k;   r = row - 512; }
    else if (row < 1024) { src = v;   r = row - 768; }
    else if (row < 1792) { src = qkv; r = row - 1024; }
    else                 { src = pw;  r = row - 1792; }
    W7[row * 256 + t] = f2bf_rne(src[r * 256 + t]);
    return;
  }
  const int xb = bx - 2048;
  const int p0 = (xb % 144) * 64;
  const int c0 = ((xb / 144) % 4) * 64;
  const int b  = xb / 576;
  const float* xb_p = x + (long)b * C * NP;
#pragma unroll
  for (int i = 0; i < 4; ++i) {
    int s = i * 256 + t;
    int c = s >> 4, p4 = s & 15;
    float4 vv = *(const float4*)&xb_p[(long)(c0 + c) * NP + p0 + p4 * 4];
    tile[c][p4 * 4 + 0] = vv.x;
    tile[c][p4 * 4 + 1] = vv.y;
    tile[c][p4 * 4 + 2] = vv.z;
    tile[c][p4 * 4 + 3] = vv.w;
  }
  __syncthreads();
  unsigned short* XTb = XT + (long)b * NP * 256;
#pragma unroll
  for (int i = 0; i < 2; ++i) {
    int s = i * 256 + t;
    int p = s >> 3, c8 = s & 7;
    unsigned short u[8];
#pragma unroll
    for (int e = 0; e < 8; ++e) u[e] = f2bf_rne(tile[c8 * 8 + e][p]);
    *(uint4*)&XTb[(long)(p0 + p) * 256 + c0 + c8 * 8] = *(const uint4*)u;
  }
}

// ---------------- bf16 transpose: ushort [c][pix] -> ushort [pix][c] -------
__global__ __launch_bounds__(256) void xpose_bf(
    const unsigned short* __restrict__ U, unsigned short* __restrict__ XT)
{
  __shared__ unsigned short tile[64][72];
  const int t = threadIdx.x;
  const int p0 = blockIdx.x * 64, c0 = blockIdx.y * 64, b = blockIdx.z;
  const unsigned short* ub = U + (long)b * C * NP;
#pragma unroll
  for (int i = 0; i < 2; ++i) {
    int s = i * 256 + t;                 // 0..511
    int c = s >> 3, p8 = s & 7;
    *(uint4*)&tile[c][p8 * 8] =
        *(const uint4*)&ub[(long)(c0 + c) * NP + p0 + p8 * 8];
  }
  __syncthreads();
  unsigned short* XTb = XT + (long)b * NP * 256;
#pragma unroll
  for (int i = 0; i < 2; ++i) {
    int s = i * 256 + t;
    int p = s >> 3, c8 = s & 7;
    unsigned short u[8];
#pragma unroll
    for (int e = 0; e < 8; ++e) u[e] = tile[c8 * 8 + e][p];
    *(uint4*)&XTb[(long)(p0 + p) * 256 + c0 + c8 * 8] = *(const uint4*)u;
  }
}

// ---------------- gemm tile body (gll staging; 2-pass within-wave epilogue) -
__device__ __forceinline__ void gemm_bt_body(
    unsigned short* smemS,
    const unsigned short* __restrict__ W, const unsigned short* __restrict__ XTb,
    unsigned short* __restrict__ Ob, int Mstride, int m0, int n0)
{
  unsigned short* As = smemS;            // [128][32] linear
  unsigned short* Bs = smemS + 4096;     // [128][32] linear

  const int t = threadIdx.x;
  const int lane = t & 63, wid = t >> 6;
  const int wm = wid >> 1, wn = wid & 1;
  const int l15 = lane & 15, l4 = lane >> 4;
  const int crow = lane >> 2;
  const int ccol = (lane & 3) * 8;

  f32x4 acc[4][4];
#pragma unroll
  for (int i = 0; i < 4; ++i)
#pragma unroll
    for (int j = 0; j < 4; ++j) acc[i][j] = (f32x4){0.f, 0.f, 0.f, 0.f};

  for (int k0 = 0; k0 < 256; k0 += 32) {
#pragma unroll
    for (int i = 0; i < 4; ++i) {
      const int ch = wid * 4 + i;
      if (ch < 8) {
        const int row = ch * 16 + crow;
        __builtin_amdgcn_global_load_lds(
            (const __attribute__((address_space(1))) unsigned int*)
                &W[(long)(m0 + row) * 256 + k0 + ccol],
            (__attribute__((address_space(3))) unsigned int*)&As[ch * 512],
            16, 0, 0);
      } else {
        const int row = (ch - 8) * 16 + crow;
        __builtin_amdgcn_global_load_lds(
            (const __attribute__((address_space(1))) unsigned int*)
                &XTb[(long)(n0 + row) * 256 + k0 + ccol],
            (__attribute__((address_space(3))) unsigned int*)&Bs[(ch - 8) * 512],
            16, 0, 0);
      }
    }
    __syncthreads();

    bf16x8 af[4], bb[4];
#pragma unroll
    for (int mf = 0; mf < 4; ++mf)
      af[mf] = *(const bf16x8*)&As[(wm * 64 + mf * 16 + l15) * 32 + l4 * 8];
#pragma unroll
    for (int nf = 0; nf < 4; ++nf)
      bb[nf] = *(const bf16x8*)&Bs[(wn * 64 + nf * 16 + l15) * 32 + l4 * 8];
#pragma unroll
    for (int mf = 0; mf < 4; ++mf)
#pragma unroll
      for (int nf = 0; nf < 4; ++nf)
        acc[mf][nf] = __builtin_amdgcn_mfma_f32_16x16x32_bf16(
            af[mf], bb[nf], acc[mf][nf], 0, 0, 0);
    __syncthreads();
  }

  // Epilogue: per-wave 32x72 region; within-wave only, no barriers.
  unsigned short* trw = smemS + wid * 2304;      // 32 * 72 shorts
  const int lp = lane >> 1;                      // local pixel 0..31
  const int cbase = (lane & 1) * 4;              // 4 chunks of 16B each
#pragma unroll
  for (int pass = 0; pass < 2; ++pass) {
#pragma unroll
    for (int nfh = 0; nfh < 2; ++nfh) {
      const int nf = pass * 2 + nfh;
#pragma unroll
      for (int mf = 0; mf < 4; ++mf) {
        unsigned u0 = (unsigned)f2bf_rne(acc[mf][nf][0]) |
                      ((unsigned)f2bf_rne(acc[mf][nf][1]) << 16);
        unsigned u1 = (unsigned)f2bf_rne(acc[mf][nf][2]) |
                      ((unsigned)f2bf_rne(acc[mf][nf][3]) << 16);
        uint2 uu; uu.x = u0; uu.y = u1;
        *(uint2*)&trw[(nfh * 16 + l15) * 72 + mf * 16 + l4 * 4] = uu;
      }
    }
    const long pix = n0 + wn * 64 + pass * 32 + lp;
    const long rowbase = pix * Mstride + m0 + wm * 64;
#pragma unroll
    for (int cc = 0; cc < 4; ++cc)
      *(uint4*)&Ob[rowbase + (cbase + cc) * 8] =
          *(const uint4*)&trw[lp * 72 + (cbase + cc) * 8];
  }
}

// ---------------- step-2 GEMM: A-phase [l2|qL|kL|vL] ------------------------
__global__ __launch_bounds__(256) void gemm_bt(
    const unsigned short* __restrict__ W, const unsigned short* __restrict__ XT,
    unsigned short* __restrict__ O, int Mstride)
{
  __shared__ __align__(16) unsigned short smemS[9216];   // 18,432 B
  gemm_bt_body(smemS, W, XT + (long)blockIdx.z * NP * 256,
               O + (long)blockIdx.z * NP * Mstride, Mstride,
               blockIdx.y * 128, blockIdx.x * 128);
}

// ---------------- local_attn body: 2D 8x4 pixel tile ------------------------
__device__ __forceinline__ void local_attn_body(
    char* smem,
    const unsigned short* __restrict__ GA, int b, int tile,
    const float* __restrict__ rel_x, const float* __restrict__ rel_y,
    const float* __restrict__ bn2_g, const float* __restrict__ bn2_b,
    const float* __restrict__ bn2_m, const float* __restrict__ bn2_v,
    const float* __restrict__ l1_bias, unsigned short* __restrict__ localO)
{
  float (*red)[32][13] = reinterpret_cast<float(*)[32][13]>(smem);   // 13312 B
  float* srel  = (float*)(smem + 13312);                             // 3072 B
  float* sS    = (float*)(smem + 16384);
  float* sO    = sS + 256;
  float* sBias = sO + 256;

  const int t = threadIdx.x;
  const int px = t & 31, ch = t >> 5;
  const int ty = tile / 24, tx = tile % 24;
  const int h = ty * 8 + (px >> 2), w = tx * 4 + (px & 3);
  const int p = h * 96 + w;
  const unsigned short* Gb = GA + (long)b * NP * 1024;

  if (t < 128) {
    srel[t * 3 + 0] = rel_x[t * 3 + 0];
    srel[t * 3 + 1] = rel_x[t * 3 + 1];
    srel[t * 3 + 2] = rel_x[t * 3 + 2];
  } else {
    int r = t - 128;
    srel[t * 3 + 0] = rel_y[r * 3 + 0];
    srel[t * 3 + 1] = rel_y[r * 3 + 1];
    srel[t * 3 + 2] = rel_y[r * 3 + 2];
  }
  {
    float s = bn2_g[t] * rsqrtf(bn2_v[t] + 1e-5f);
    sS[t] = s;
    sO[t] = bn2_b[t] - bn2_m[t] * s;
    sBias[t] = l1_bias[t];
  }

  int nof[9];
  float msk[9];
#pragma unroll
  for (int ky = 0; ky < 3; ++ky)
#pragma unroll
    for (int kx = 0; kx < 3; ++kx) {
      int j = ky * 3 + kx, hn = h + ky - 1, wn = w + kx - 1;
      bool v = (hn >= 0 && hn < 96 && wn >= 0 && wn < 96);
      nof[j] = v ? hn * 96 + wn : p;
      msk[j] = v ? 1.f : 0.f;
    }
  __syncthreads();

  float lg[9] = {0, 0, 0, 0, 0, 0, 0, 0, 0};
  float rq[3] = {0, 0, 0};
  const int c0 = ch * 32;
#pragma unroll
  for (int i = 0; i < 4; ++i) {
    const int c = c0 + i * 8;
    bf16x8 q8 = *(const bf16x8*)&Gb[(long)p * 1024 + 256 + c];
    float qv[8];
#pragma unroll
    for (int e = 0; e < 8; ++e) qv[e] = (float)q8[e];
#pragma unroll
    for (int j = 0; j < 9; ++j) {
      bf16x8 k8 = *(const bf16x8*)&Gb[(long)nof[j] * 1024 + 512 + c];
#pragma unroll
      for (int e = 0; e < 8; ++e) lg[j] += qv[e] * (float)k8[e];
    }
#pragma unroll
    for (int e = 0; e < 8; ++e) {
      const float* sr = &srel[(c + e) * 3];
      rq[0] += qv[e] * sr[0];
      rq[1] += qv[e] * sr[1];
      rq[2] += qv[e] * sr[2];
    }
  }
#pragma unroll
  for (int j = 0; j < 9; ++j) red[ch][px][j] = lg[j] * msk[j];
#pragma unroll
  for (int l = 0; l < 3; ++l) red[ch][px][9 + l] = rq[l];
  __syncthreads();

  float a[9];
  float mx = -1e30f;
#pragma unroll
  for (int j = 0; j < 9; ++j) {
    float v = 0.f;
#pragma unroll
    for (int u = 0; u < 8; ++u) v += red[u][px][j];
    float qxl = red[0][px][9 + j % 3] + red[1][px][9 + j % 3] +
                red[2][px][9 + j % 3] + red[3][px][9 + j % 3];
    float qyk = red[4][px][9 + j / 3] + red[5][px][9 + j / 3] +
                red[6][px][9 + j / 3] + red[7][px][9 + j / 3];
    a[j] = v + qxl + qyk;
    mx = fmaxf(mx, a[j]);
  }
  float sum = 0.f;
#pragma unroll
  for (int j = 0; j < 9; ++j) { a[j] = __expf(a[j] - mx); sum += a[j]; }
  const float inv = 1.f / sum;
  float am[9];
#pragma unroll
  for (int j = 0; j < 9; ++j) am[j] = a[j] * inv * msk[j];

#pragma unroll
  for (int i = 0; i < 4; ++i) {
    const int c = c0 + i * 8;
    bf16x8 l28 = *(const bf16x8*)&Gb[(long)p * 1024 + 0 + c];
    float o8[8] = {0, 0, 0, 0, 0, 0, 0, 0};
#pragma unroll
    for (int j = 0; j < 9; ++j) {
      bf16x8 v8 = *(const bf16x8*)&Gb[(long)nof[j] * 1024 + 768 + c];
#pragma unroll
      for (int e = 0; e < 8; ++e) o8[e] += am[j] * (float)v8[e];
    }
#pragma unroll
    for (int e = 0; e < 8; ++e) {
      const int cg = c + e;
      localO[((long)b * C + cg) * NP + p] = f2bf_rne(
          (float)l28[e] * sS[cg] + sO[cg] + o8[e] + sBias[cg]);
    }
  }
}

// ---------------- FUSED: qkv GEMM ∥ local_attn, roles interleaved 3:2 ------
__global__ __launch_bounds__(256) void la_qkv(
    const unsigned short* __restrict__ Wqkv, const unsigned short* __restrict__ XT,
    unsigned short* __restrict__ GB, const unsigned short* __restrict__ GA,
    const float* __restrict__ rel_x, const float* __restrict__ rel_y,
    const float* __restrict__ bn2_g, const float* __restrict__ bn2_b,
    const float* __restrict__ bn2_m, const float* __restrict__ bn2_v,
    const float* __restrict__ l1_bias, unsigned short* __restrict__ localO)
{
  __shared__ __align__(16) char smem[19456];
  const int bx = blockIdx.x;             // 1440 = 288 groups of 5 (3 gemm+2 la)
  const int g = bx / 5, r = bx % 5;
  if (r < 3) {
    const int gi = g * 3 + r;            // 0..863
    const int n = gi % 72, rest = gi / 72;
    const int m = rest % 6, b = rest / 6;
    gemm_bt_body((unsigned short*)smem, Wqkv, XT + (long)b * NP * 256,
                 GB + (long)b * NP * 768, 768, m * 128, n * 128);
  } else {
    const int li = g * 2 + (r - 3);      // 0..575
    const int orig = li % 288, b = li / 288;
    // XCD-aware bijective swizzle (288 % 8 == 0)
    const int tile = (orig & 7) * 36 + (orig >> 3);
    local_attn_body(smem, GA, b, tile, rel_x, rel_y, bn2_g, bn2_b, bn2_m,
                    bn2_v, l1_bias, localO);
  }
}

// ---------------- bf16 GEMM, fp32 channel-major out, 64x128 tile (pw) ------
__global__ __launch_bounds__(256) void gemm_cf32(
    const unsigned short* __restrict__ W, const unsigned short* __restrict__ XT,
    float* __restrict__ Co)
{
  __shared__ unsigned short As[64][40];
  __shared__ unsigned short Bs[128][40];

  const int t = threadIdx.x;
  const int lane = t & 63, wid = t >> 6;
  const int wm = wid >> 1, wn = wid & 1;
  const int l15 = lane & 15, l4 = lane >> 4;
  const int n0 = blockIdx.x * 128, m0 = blockIdx.y * 64;
  const unsigned short* XTb = XT + (long)blockIdx.z * NP * 256;
  float* Cb = Co + (long)blockIdx.z * C * NP;

  f32x4 acc[2][4];
#pragma unroll
  for (int i = 0; i < 2; ++i)
#pragma unroll
    for (int j = 0; j < 4; ++j) acc[i][j] = (f32x4){0.f, 0.f, 0.f, 0.f};

  for (int k0 = 0; k0 < 256; k0 += 32) {
    {
      int r = t >> 2, kc = t & 3;
      *(uint4*)&As[r][kc * 8] =
          *(const uint4*)&W[(long)(m0 + r) * 256 + k0 + kc * 8];
    }
#pragma unroll
    for (int i = 0; i < 2; ++i) {
      int s = i * 256 + t, r = s >> 2, kc = s & 3;
      *(uint4*)&Bs[r][kc * 8] =
          *(const uint4*)&XTb[(long)(n0 + r) * 256 + k0 + kc * 8];
    }
    __syncthreads();

    bf16x8 af[2], bb[4];
#pragma unroll
    for (int mf = 0; mf < 2; ++mf)
      af[mf] = *(const bf16x8*)&As[wm * 32 + mf * 16 + l15][l4 * 8];
#pragma unroll
    for (int nf = 0; nf < 4; ++nf)
      bb[nf] = *(const bf16x8*)&Bs[wn * 64 + nf * 16 + l15][l4 * 8];
#pragma unroll
    for (int mf = 0; mf < 2; ++mf)
#pragma unroll
      for (int nf = 0; nf < 4; ++nf)
        acc[mf][nf] = __builtin_amdgcn_mfma_f32_16x16x32_bf16(
            af[mf], bb[nf], acc[mf][nf], 0, 0, 0);
    __syncthreads();
  }

#pragma unroll
  for (int mf = 0; mf < 2; ++mf)
#pragma unroll
    for (int r = 0; r < 4; ++r) {
      int row = m0 + wm * 32 + mf * 16 + l4 * 4 + r;
#pragma unroll
      for (int nf = 0; nf < 4; ++nf) {
        int col = n0 + wn * 64 + nf * 16 + l15;
        Cb[(long)row * NP + col] = acc[mf][nf][r];
      }
    }
}

// ---------------- 8x8 window attention via MFMA -> bf16 --------------------
__global__ __launch_bounds__(64) void window_attn_mfma(
    const unsigned short* __restrict__ QKV,
    const float* __restrict__ rel_table, unsigned short* __restrict__ attnO)
{
  const int win = blockIdx.x, hd = blockIdx.y, b = blockIdx.z;
  const int wy = win / 12, wx = win % 12;
  const int lane = threadIdx.x;
  const int l15 = lane & 15, hi4 = lane >> 4;
  const int l31 = lane & 31, hi2 = lane >> 5;

  __shared__ float srpb[225];
  __shared__ __bf16 P[64][72];

  for (int i = lane; i < 225; i += 64) srpb[i] = rel_table[i * 16 + hd];

  const __bf16* base = (const __bf16*)QKV + (long)b * 9216 * 768;
  const int pixbase = (wy * 8) * 96 + wx * 8;

#define WPIX(i) (pixbase + ((i) >> 3) * 96 + ((i) & 7))

  bf16x8 kf[2], qf[2];
#pragma unroll
  for (int kt = 0; kt < 2; ++kt)
    kf[kt] = *(const bf16x8*)&base[(long)WPIX(32 * kt + l31) * 768 + 256 +
                                   hd * 16 + hi2 * 8];
#pragma unroll
  for (int qt = 0; qt < 2; ++qt)
    qf[qt] = *(const bf16x8*)&base[(long)WPIX(32 * qt + l31) * 768 +
                                   hd * 16 + hi2 * 8];

  bf16x8 vf[2];
#pragma unroll
  for (int kc = 0; kc < 2; ++kc)
#pragma unroll
    for (int j = 0; j < 8; ++j)
      vf[kc][j] = base[(long)WPIX(32 * kc + 8 * hi4 + j) * 768 + 512 +
                       hd * 16 + l15];

  f32x16 S[2][2];
#pragma unroll
  for (int kt = 0; kt < 2; ++kt)
#pragma unroll
    for (int qt = 0; qt < 2; ++qt)
#pragma unroll
      for (int r = 0; r < 16; ++r) S[kt][qt][r] = 0.f;

#pragma unroll
  for (int kt = 0; kt < 2; ++kt)
#pragma unroll
    for (int qt = 0; qt < 2; ++qt)
      S[kt][qt] = __builtin_amdgcn_mfma_f32_32x32x16_bf16(
          kf[kt], qf[qt], S[kt][qt], 0, 0, 0);

  __syncthreads();

  float mx[2] = {-1e30f, -1e30f};
#pragma unroll
  for (int kt = 0; kt < 2; ++kt)
#pragma unroll
    for (int r = 0; r < 16; ++r) {
      const int key = 32 * kt + (r & 3) + 8 * (r >> 2) + 4 * hi2;
      const int ky = key >> 3, kx = key & 7;
#pragma unroll
      for (int qt = 0; qt < 2; ++qt) {
        const int q = 32 * qt + l31;
        const int qy = q >> 3, qx = q & 7;
        float s = S[kt][qt][r] * 0.25f + srpb[(qy - ky + 7) * 15 + (qx - kx + 7)];
        S[kt][qt][r] = s;
        mx[qt] = fmaxf(mx[qt], s);
      }
    }
#pragma unroll
  for (int qt = 0; qt < 2; ++qt)
    mx[qt] = fmaxf(mx[qt], __shfl_xor(mx[qt], 32));

  float sum[2] = {0.f, 0.f};
#pragma unroll
  for (int kt = 0; kt < 2; ++kt)
#pragma unroll
    for (int qt = 0; qt < 2; ++qt)
#pragma unroll
      for (int r = 0; r < 16; ++r) {
        float e = __expf(S[kt][qt][r] - mx[qt]);
        S[kt][qt][r] = e;
        sum[qt] += e;
      }
#pragma unroll
  for (int qt = 0; qt < 2; ++qt) sum[qt] += __shfl_xor(sum[qt], 32);
  const float inv0 = 1.f / sum[0], inv1 = 1.f / sum[1];

#pragma unroll
  for (int qt = 0; qt < 2; ++qt) {
    const float inv = qt ? inv1 : inv0;
#pragma unroll
    for (int kt = 0; kt < 2; ++kt)
#pragma unroll
      for (int rq = 0; rq < 4; ++rq) {
        bf16x4 pk;
#pragma unroll
        for (int j = 0; j < 4; ++j) pk[j] = f2bf16(S[kt][qt][rq * 4 + j] * inv);
        *(bf16x4*)&P[32 * qt + l31][32 * kt + 8 * rq + 4 * hi2] = pk;
      }
  }
  __syncthreads();

  f32x4 o[4];
#pragma unroll
  for (int qt4 = 0; qt4 < 4; ++qt4) o[qt4] = (f32x4){0.f, 0.f, 0.f, 0.f};
#pragma unroll
  for (int kc = 0; kc < 2; ++kc)
#pragma unroll
    for (int qt4 = 0; qt4 < 4; ++qt4) {
      bf16x8 pf = *(const bf16x8*)&P[16 * qt4 + l15][32 * kc + 8 * hi4];
      o[qt4] = __builtin_amdgcn_mfma_f32_16x16x32_bf16(vf[kc], pf, o[qt4], 0, 0, 0);
    }

#pragma unroll
  for (int qt4 = 0; qt4 < 4; ++qt4)
#pragma unroll
    for (int r = 0; r < 4; ++r) {
      const int q = 16 * qt4 + l15;
      attnO[((long)b * C + hd * 16 + 4 * hi4 + r) * NP + WPIX(q)] =
          f2bf_rne(o[qt4][r]);
    }
#undef WPIX
}

// ---------------- fused pools + combine + dw conv + BN -> bf16 out ---------
__global__ __launch_bounds__(128) void pool_dw8(
    const unsigned short* __restrict__ attn,
    const unsigned short* __restrict__ localO,
    const float* __restrict__ dww,
    const float* __restrict__ bnp_g, const float* __restrict__ bnp_b,
    const float* __restrict__ bnp_m, const float* __restrict__ bnp_v,
    unsigned short* __restrict__ dst)
{
  const int r0 = blockIdx.x * 12;
  const int c = blockIdx.y, b = blockIdx.z;
  const int t = threadIdx.x;

  __shared__ float img[26 * 116];
  __shared__ float img2[19 * 108];

  const unsigned short* A = attn + ((long)b * C + c) * NP;
  const unsigned short* L = localO + ((long)b * C + c) * NP;

  for (int idx = t; idx < 26 * 28; idx += 128) {
    const int j = idx / 28, k = idx % 28;
    const int R = r0 - 6 + j;
    const bool rv = (R >= 0 && R <= 96);
    const int Rc = (R == 96) ? 94 : (rv ? R : 0);
    const int s0 = 4 * k - 8;
    float4 v = {-1e30f, -1e30f, -1e30f, -1e30f};
    if (rv && s0 >= 0 && s0 <= 92) v = bf4_to_f4(&A[Rc * 96 + s0]);
    else if (rv && s0 == 96) v.x = bf2f(A[Rc * 96 + 94]);
    *(float4*)&img[j * 116 + 4 * k] = v;
  }
  for (int idx = t; idx < 19 * 27; idx += 128) {
    const int j2 = idx / 27, g = idx % 27;
    const int R2 = r0 - 3 + j2;
    const bool rv = (R2 >= 0 && R2 <= 96);
    const int R2c = (R2 == 96) ? 94 : (rv ? R2 : 0);
    const int w0 = 4 * g - 4;
    float4 v = {0.f, 0.f, 0.f, 0.f};
    if (rv) {
      if (w0 >= 0 && w0 <= 92) v = bf4_to_f4(&L[R2c * 96 + w0]);
      else if (w0 == 96) v.x = bf2f(L[R2c * 96 + 94]);
    }
    *(float4*)&img2[j2 * 108 + 4 * g] = v;
  }
  float wr[64];
#pragma unroll
  for (int i = 0; i < 64; ++i) wr[i] = dww[c * 64 + i];
  const float scl = bnp_g[c] * rsqrtf(bnp_v[c] + 1e-5f);
  const float off = bnp_b[c] - bnp_m[c] * scl;
  __syncthreads();

  const int j2lo = (r0 == 0) ? 3 : 0;
  const int j2hi = (r0 == 84) ? 14 : 18;
  if (t < 120) {
    const int blk = t / 24, G = t % 24;
    const int j2b = j2lo + blk * 4;
    if (j2b <= j2hi) {
      float4 hc[11];
#pragma unroll
      for (int ii = 0; ii < 11; ++ii) {
        int rr = j2b + ii;
        rr = (rr > 25) ? 25 : rr;
        hc[ii] = *(const float4*)&img[rr * 116 + 4 * G + 8];
      }
#pragma unroll
      for (int r = 0; r < 4; ++r) {
        const int j2 = j2b + r;
        if (j2 > j2hi) break;
        float mph[4] = {-1e30f, -1e30f, -1e30f, -1e30f};
        float aph[4] = {0.f, 0.f, 0.f, 0.f};
#pragma unroll
        for (int ii = 0; ii < 8; ++ii) {
          const float h4[4] = {hc[r + ii].x, hc[r + ii].y, hc[r + ii].z,
                               hc[r + ii].w};
#pragma unroll
          for (int d = 0; d < 4; ++d) {
            mph[d] = fmaxf(mph[d], h4[d]);
            aph[d] += (h4[d] > -1e29f) ? h4[d] : 0.f;
          }
        }
        float rw[12];
        {
          const float* row = &img[(j2 + 3) * 116 + 4 * G + 4];
          float4 a0 = *(const float4*)&row[0];
          float4 a1 = *(const float4*)&row[4];
          float4 a2 = *(const float4*)&row[8];
          rw[0] = a0.x; rw[1] = a0.y; rw[2] = a0.z; rw[3] = a0.w;
          rw[4] = a1.x; rw[5] = a1.y; rw[6] = a1.z; rw[7] = a1.w;
          rw[8] = a2.x; rw[9] = a2.y; rw[10] = a2.z; rw[11] = a2.w;
        }
        float4 lv = *(const float4*)&img2[j2 * 108 + 4 * G + 4];
        const float l4[4] = {lv.x, lv.y, lv.z, lv.w};
        float o4[4];
#pragma unroll
        for (int d = 0; d < 4; ++d) {
          float mpw = -1e30f, apw = 0.f;
#pragma unroll
          for (int ii = 0; ii < 8; ++ii) {
            const float wv = rw[d + 1 + ii];
            mpw = fmaxf(mpw, wv);
            apw += (wv > -1e29f) ? wv : 0.f;
          }
          o4[d] = mph[d] + mpw + (aph[d] + apw) * 0.125f + l4[d];
        }
        float4 out;
        out.x = o4[0]; out.y = o4[1]; out.z = o4[2]; out.w = o4[3];
        *(float4*)&img2[j2 * 108 + 4 * G + 4] = out;
        if (G == 23) img2[j2 * 108 + 100] = o4[2];
        if (r0 == 84 && j2 == 13) {
          *(float4*)&img2[15 * 108 + 4 * G + 4] = out;
          if (G == 23) img2[15 * 108 + 100] = o4[2];
        }
      }
    }
  }
  __syncthreads();

  if (t < 72) {
    const int cb = t / 24, ocg = t % 24;
    const int hh0 = cb * 4;
    float acc[4][4];
#pragma unroll
    for (int o = 0; o < 4; ++o)
#pragma unroll
      for (int d = 0; d < 4; ++d) acc[o][d] = 0.f;
#pragma unroll
    for (int i = 0; i < 11; ++i) {
      const float* row = &img2[(hh0 + i) * 108 + 4 * ocg];
      float w12[12];
      {
        float4 a0 = *(const float4*)&row[0];
        float4 a1 = *(const float4*)&row[4];
        float4 a2 = *(const float4*)&row[8];
        w12[0] = a0.x; w12[1] = a0.y; w12[2] = a0.z; w12[3] = a0.w;
        w12[4] = a1.x; w12[5] = a1.y; w12[6] = a1.z; w12[7] = a1.w;
        w12[8] = a2.x; w12[9] = a2.y; w12[10] = a2.z; w12[11] = a2.w;
      }
#pragma unroll
      for (int o = 0; o < 4; ++o) {
        if (o > i || i - o > 7) continue;
        const int ir = i - o;
#pragma unroll
        for (int d = 0; d < 4; ++d)
#pragma unroll
          for (int jj = 0; jj < 8; ++jj)
            acc[o][d] = fmaf(wr[ir * 8 + jj], w12[d + 1 + jj], acc[o][d]);
      }
    }
#pragma unroll
    for (int o = 0; o < 4; ++o) {
      unsigned short u4[4];
#pragma unroll
      for (int d = 0; d < 4; ++d) u4[d] = f2bf_rne(acc[o][d] * scl + off);
      *(uint2*)&dst[((long)b * C + c) * NP + (r0 + hh0 + o) * 96 + 4 * ocg] =
          *(const uint2*)u4;
    }
  }
}

}  // namespace

extern "C" void kernel_launch(void* const* d_in, const int* in_sizes, int n_in,
                              void* d_out, int out_size, void* d_ws, size_t ws_size,
                              hipStream_t stream) {
  const float* x         = (const float*)d_in[0];
  const float* qkv_w     = (const float*)d_in[1];
  const float* l2_w      = (const float*)d_in[2];
  const float* bn2_g     = (const float*)d_in[3];
  const float* bn2_b     = (const float*)d_in[4];
  const float* bn2_m     = (const float*)d_in[5];
  const float* bn2_v     = (const float*)d_in[6];
  const float* wq        = (const float*)d_in[7];
  const float* wk        = (const float*)d_in[8];
  const float* wv        = (const float*)d_in[9];
  const float* rel_x     = (const float*)d_in[10];
  const float* rel_y     = (const float*)d_in[11];
  const float* l1_bias   = (const float*)d_in[12];
  const float* rel_table = (const float*)d_in[13];
  const float* dw_w      = (const float*)d_in[14];
  const float* bnp_g     = (const float*)d_in[15];
  const float* bnp_b     = (const float*)d_in[16];
  const float* bnp_m     = (const float*)d_in[17];
  const float* bnp_v     = (const float*)d_in[18];
  const float* pw_w      = (const float*)d_in[19];
  float* out = (float*)d_out;
  float* ws  = (float*)d_ws;

  unsigned short* GA     = (unsigned short*)ws;                      // [0,9.44M)
  unsigned short* GB     = (unsigned short*)(ws + 9437184);          // 7.08M
  unsigned short* localB = (unsigned short*)(ws + 16515072);         // 2.36M
  unsigned short* W7     = (unsigned short*)(ws + 18874368);         // 0.26M
  unsigned short* XT     = (unsigned short*)(ws + 19136512);         // 2.36M
  unsigned short* attnB  = (unsigned short*)(ws + 19136512);         // alias XT
  unsigned short* dwB    = (unsigned short*)ws;                      // over GA
  unsigned short* XT2    = (unsigned short*)(ws + 4718592);          // over GA

  // 1. prep: weights -> W7 (blocks 0..2047) + x -> XT (blocks 2048..3199)
  prep<<<dim3(3200), 256, 0, stream>>>(x, l2_w, wq, wk, wv, qkv_w, pw_w,
                                       XT, W7);

  // 2. [l2|qL|kL|vL] -> GA bf16 [pix][1024]
  gemm_bt<<<dim3(72, 8, 2), 256, 0, stream>>>(W7, XT, GA, 1024);

  // 3. FUSED: qkv GEMM -> GB  ∥  neighborhood attention -> localB
  la_qkv<<<dim3(1440), 256, 0, stream>>>(W7 + 1024 * 256, XT, GB, GA,
                                         rel_x, rel_y, bn2_g, bn2_b, bn2_m,
                                         bn2_v, l1_bias, localB);

  // 4. window attention (MFMA) -> attnB (over dead XT)
  window_attn_mfma<<<dim3(144, 16, 2), 64, 0, stream>>>(GB, rel_table, attnB);

  // 5. pools + combine + depthwise conv + BN -> dwB bf16 (over dead GA)
  pool_dw8<<<dim3(8, 256, 2), 128, 0, stream>>>(attnB, localB, dw_w, bnp_g,
                                                bnp_b, bnp_m, bnp_v, dwB);

  // 6. dwB bf16 -> XT2 bf16 [pix][256]
  xpose_bf<<<dim3(144, 4, 2), 256, 0, stream>>>(dwB, XT2);

  // 7. pointwise GEMM -> out (fp32 channel-major, 64x128 tiles)
  gemm_cf32<<<dim3(72, 4, 2), 256, 0, stream>>>(W7 + 1792 * 256, XT2, out);
}

// Round 18
// 165.166 us; speedup vs baseline: 1.0273x; 1.0074x over previous
//
#include <hip/hip_runtime.h>
#include <math.h>

// GlobalLocalAttention — round 17: R16 + conflict-free xpose_bf (stride 66
// shorts: 2-way banks on both phases, vs 8-way at stride 72).
//
// Pipeline:
//  1. prep:    {x -> XT bf16}  ∪  {weights -> W7 bf16}
//  2. gemm_bt(W7[0:1024])    -> GA bf16 [b][NP][1024]
//  3. la_qkv:  {gemm qkv -> GB}  ∥  {local_attn(GA) -> localB}  (3:2 interleave)
//  4. window_attn_mfma(GB)   -> attnB bf16 (aliases XT, dead)
//  5. pool_dw8               -> dwB bf16 (over dead GA)
//  6. xpose_bf(dwB)          -> XT2 bf16
//  7. gemm_cf32(W7[1792:2048], XT2) -> d_out

namespace {

constexpr int NP = 96 * 96;   // 9216
constexpr int C  = 256;

typedef __bf16 bf16x8 __attribute__((ext_vector_type(8)));
typedef __bf16 bf16x4 __attribute__((ext_vector_type(4)));
typedef float  f32x4  __attribute__((ext_vector_type(4)));
typedef float  f32x16 __attribute__((ext_vector_type(16)));

__device__ __forceinline__ unsigned short f2bf_rne(float f) {
  unsigned u = __float_as_uint(f);
  u += 0x7FFFu + ((u >> 16) & 1u);
  return (unsigned short)(u >> 16);
}
__device__ __forceinline__ __bf16 f2bf16(float f) {
  unsigned short s = f2bf_rne(f);
  return *(__bf16*)&s;
}
__device__ __forceinline__ float bf2f(unsigned short s) {
  unsigned u = (unsigned)s << 16;
  return __uint_as_float(u);
}
__device__ __forceinline__ float4 bf4_to_f4(const unsigned short* p) {
  bf16x4 v = *(const bf16x4*)p;
  float4 r;
  r.x = (float)v[0]; r.y = (float)v[1]; r.z = (float)v[2]; r.w = (float)v[3];
  return r;
}

// ---------------- merged prep: weight cvt (blocks 0..2047) + x transpose ----
__global__ __launch_bounds__(256) void prep(
    const float* __restrict__ x,
    const float* __restrict__ l2, const float* __restrict__ q,
    const float* __restrict__ k,  const float* __restrict__ v,
    const float* __restrict__ qkv, const float* __restrict__ pw,
    unsigned short* __restrict__ XT, unsigned short* __restrict__ W7)
{
  __shared__ float tile[64][65];
  const int bx = blockIdx.x;
  const int t = threadIdx.x;
  if (bx < 2048) {
    const int row = bx;
    const float* src; int r;
    if      (row <  256) { src = l2;  r = row; }
    else if (row <  512) { src = q;   r = row - 256; }
    else if (row <  768) { src = k;   r = row - 512; }
    else if (row < 1024) { src = v;   r = row - 768; }
    else if (row < 1792) { src = qkv; r = row - 1024; }
    else                 { src = pw;  r = row - 1792; }
    W7[row * 256 + t] = f2bf_rne(src[r * 256 + t]);
    return;
  }
  const int xb = bx - 2048;
  const int p0 = (xb % 144) * 64;
  const int c0 = ((xb / 144) % 4) * 64;
  const int b  = xb / 576;
  const float* xb_p = x + (long)b * C * NP;
#pragma unroll
  for (int i = 0; i < 4; ++i) {
    int s = i * 256 + t;
    int c = s >> 4, p4 = s & 15;
    float4 vv = *(const float4*)&xb_p[(long)(c0 + c) * NP + p0 + p4 * 4];
    tile[c][p4 * 4 + 0] = vv.x;
    tile[c][p4 * 4 + 1] = vv.y;
    tile[c][p4 * 4 + 2] = vv.z;
    tile[c][p4 * 4 + 3] = vv.w;
  }
  __syncthreads();
  unsigned short* XTb = XT + (long)b * NP * 256;
#pragma unroll
  for (int i = 0; i < 2; ++i) {
    int s = i * 256 + t;
    int p = s >> 3, c8 = s & 7;
    unsigned short u[8];
#pragma unroll
    for (int e = 0; e < 8; ++e) u[e] = f2bf_rne(tile[c8 * 8 + e][p]);
    *(uint4*)&XTb[(long)(p0 + p) * 256 + c0 + c8 * 8] = *(const uint4*)u;
  }
}

// ---------------- bf16 transpose: ushort [c][pix] -> ushort [pix][c] -------
// tile stride 66 shorts: write banks (33c+4p8+j)%32 = 2 lanes/bank (free);
// read banks delta 8*66*2/4 = 264 % 32 = 8 -> 2-way (free).
__global__ __launch_bounds__(256) void xpose_bf(
    const unsigned short* __restrict__ U, unsigned short* __restrict__ XT)
{
  __shared__ unsigned short tile[64][66];
  const int t = threadIdx.x;
  const int p0 = blockIdx.x * 64, c0 = blockIdx.y * 64, b = blockIdx.z;
  const unsigned short* ub = U + (long)b * C * NP;
#pragma unroll
  for (int i = 0; i < 2; ++i) {
    int s = i * 256 + t;                 // 0..511
    int c = s >> 3, p8 = s & 7;
    uint4 v = *(const uint4*)&ub[(long)(c0 + c) * NP + p0 + p8 * 8];
    unsigned* d = (unsigned*)&tile[c][p8 * 8];   // 4B-aligned (132*c % 4 == 0)
    d[0] = v.x; d[1] = v.y; d[2] = v.z; d[3] = v.w;
  }
  __syncthreads();
  unsigned short* XTb = XT + (long)b * NP * 256;
#pragma unroll
  for (int i = 0; i < 2; ++i) {
    int s = i * 256 + t;
    int p = s >> 3, c8 = s & 7;
    unsigned short u[8];
#pragma unroll
    for (int e = 0; e < 8; ++e) u[e] = tile[c8 * 8 + e][p];
    *(uint4*)&XTb[(long)(p0 + p) * 256 + c0 + c8 * 8] = *(const uint4*)u;
  }
}

// ---------------- gemm tile body (gll staging; 2-pass within-wave epilogue) -
__device__ __forceinline__ void gemm_bt_body(
    unsigned short* smemS,
    const unsigned short* __restrict__ W, const unsigned short* __restrict__ XTb,
    unsigned short* __restrict__ Ob, int Mstride, int m0, int n0)
{
  unsigned short* As = smemS;            // [128][32] linear
  unsigned short* Bs = smemS + 4096;     // [128][32] linear

  const int t = threadIdx.x;
  const int lane = t & 63, wid = t >> 6;
  const int wm = wid >> 1, wn = wid & 1;
  const int l15 = lane & 15, l4 = lane >> 4;
  const int crow = lane >> 2;
  const int ccol = (lane & 3) * 8;

  f32x4 acc[4][4];
#pragma unroll
  for (int i = 0; i < 4; ++i)
#pragma unroll
    for (int j = 0; j < 4; ++j) acc[i][j] = (f32x4){0.f, 0.f, 0.f, 0.f};

  for (int k0 = 0; k0 < 256; k0 += 32) {
#pragma unroll
    for (int i = 0; i < 4; ++i) {
      const int ch = wid * 4 + i;
      if (ch < 8) {
        const int row = ch * 16 + crow;
        __builtin_amdgcn_global_load_lds(
            (const __attribute__((address_space(1))) unsigned int*)
                &W[(long)(m0 + row) * 256 + k0 + ccol],
            (__attribute__((address_space(3))) unsigned int*)&As[ch * 512],
            16, 0, 0);
      } else {
        const int row = (ch - 8) * 16 + crow;
        __builtin_amdgcn_global_load_lds(
            (const __attribute__((address_space(1))) unsigned int*)
                &XTb[(long)(n0 + row) * 256 + k0 + ccol],
            (__attribute__((address_space(3))) unsigned int*)&Bs[(ch - 8) * 512],
            16, 0, 0);
      }
    }
    __syncthreads();

    bf16x8 af[4], bb[4];
#pragma unroll
    for (int mf = 0; mf < 4; ++mf)
      af[mf] = *(const bf16x8*)&As[(wm * 64 + mf * 16 + l15) * 32 + l4 * 8];
#pragma unroll
    for (int nf = 0; nf < 4; ++nf)
      bb[nf] = *(const bf16x8*)&Bs[(wn * 64 + nf * 16 + l15) * 32 + l4 * 8];
#pragma unroll
    for (int mf = 0; mf < 4; ++mf)
#pragma unroll
      for (int nf = 0; nf < 4; ++nf)
        acc[mf][nf] = __builtin_amdgcn_mfma_f32_16x16x32_bf16(
            af[mf], bb[nf], acc[mf][nf], 0, 0, 0);
    __syncthreads();
  }

  // Epilogue: per-wave 32x72 region; within-wave only, no barriers.
  unsigned short* trw = smemS + wid * 2304;      // 32 * 72 shorts
  const int lp = lane >> 1;                      // local pixel 0..31
  const int cbase = (lane & 1) * 4;              // 4 chunks of 16B each
#pragma unroll
  for (int pass = 0; pass < 2; ++pass) {
#pragma unroll
    for (int nfh = 0; nfh < 2; ++nfh) {
      const int nf = pass * 2 + nfh;
#pragma unroll
      for (int mf = 0; mf < 4; ++mf) {
        unsigned u0 = (unsigned)f2bf_rne(acc[mf][nf][0]) |
                      ((unsigned)f2bf_rne(acc[mf][nf][1]) << 16);
        unsigned u1 = (unsigned)f2bf_rne(acc[mf][nf][2]) |
                      ((unsigned)f2bf_rne(acc[mf][nf][3]) << 16);
        uint2 uu; uu.x = u0; uu.y = u1;
        *(uint2*)&trw[(nfh * 16 + l15) * 72 + mf * 16 + l4 * 4] = uu;
      }
    }
    const long pix = n0 + wn * 64 + pass * 32 + lp;
    const long rowbase = pix * Mstride + m0 + wm * 64;
#pragma unroll
    for (int cc = 0; cc < 4; ++cc)
      *(uint4*)&Ob[rowbase + (cbase + cc) * 8] =
          *(const uint4*)&trw[lp * 72 + (cbase + cc) * 8];
  }
}

// ---------------- step-2 GEMM: A-phase [l2|qL|kL|vL] ------------------------
__global__ __launch_bounds__(256) void gemm_bt(
    const unsigned short* __restrict__ W, const unsigned short* __restrict__ XT,
    unsigned short* __restrict__ O, int Mstride)
{
  __shared__ __align__(16) unsigned short smemS[9216];   // 18,432 B
  gemm_bt_body(smemS, W, XT + (long)blockIdx.z * NP * 256,
               O + (long)blockIdx.z * NP * Mstride, Mstride,
               blockIdx.y * 128, blockIdx.x * 128);
}

// ---------------- local_attn body: 2D 8x4 pixel tile ------------------------
__device__ __forceinline__ void local_attn_body(
    char* smem,
    const unsigned short* __restrict__ GA, int b, int tile,
    const float* __restrict__ rel_x, const float* __restrict__ rel_y,
    const float* __restrict__ bn2_g, const float* __restrict__ bn2_b,
    const float* __restrict__ bn2_m, const float* __restrict__ bn2_v,
    const float* __restrict__ l1_bias, unsigned short* __restrict__ localO)
{
  float (*red)[32][13] = reinterpret_cast<float(*)[32][13]>(smem);   // 13312 B
  float* srel  = (float*)(smem + 13312);                             // 3072 B
  float* sS    = (float*)(smem + 16384);
  float* sO    = sS + 256;
  float* sBias = sO + 256;

  const int t = threadIdx.x;
  const int px = t & 31, ch = t >> 5;
  const int ty = tile / 24, tx = tile % 24;
  const int h = ty * 8 + (px >> 2), w = tx * 4 + (px & 3);
  const int p = h * 96 + w;
  const unsigned short* Gb = GA + (long)b * NP * 1024;

  if (t < 128) {
    srel[t * 3 + 0] = rel_x[t * 3 + 0];
    srel[t * 3 + 1] = rel_x[t * 3 + 1];
    srel[t * 3 + 2] = rel_x[t * 3 + 2];
  } else {
    int r = t - 128;
    srel[t * 3 + 0] = rel_y[r * 3 + 0];
    srel[t * 3 + 1] = rel_y[r * 3 + 1];
    srel[t * 3 + 2] = rel_y[r * 3 + 2];
  }
  {
    float s = bn2_g[t] * rsqrtf(bn2_v[t] + 1e-5f);
    sS[t] = s;
    sO[t] = bn2_b[t] - bn2_m[t] * s;
    sBias[t] = l1_bias[t];
  }

  int nof[9];
  float msk[9];
#pragma unroll
  for (int ky = 0; ky < 3; ++ky)
#pragma unroll
    for (int kx = 0; kx < 3; ++kx) {
      int j = ky * 3 + kx, hn = h + ky - 1, wn = w + kx - 1;
      bool v = (hn >= 0 && hn < 96 && wn >= 0 && wn < 96);
      nof[j] = v ? hn * 96 + wn : p;
      msk[j] = v ? 1.f : 0.f;
    }
  __syncthreads();

  float lg[9] = {0, 0, 0, 0, 0, 0, 0, 0, 0};
  float rq[3] = {0, 0, 0};
  const int c0 = ch * 32;
#pragma unroll
  for (int i = 0; i < 4; ++i) {
    const int c = c0 + i * 8;
    bf16x8 q8 = *(const bf16x8*)&Gb[(long)p * 1024 + 256 + c];
    float qv[8];
#pragma unroll
    for (int e = 0; e < 8; ++e) qv[e] = (float)q8[e];
#pragma unroll
    for (int j = 0; j < 9; ++j) {
      bf16x8 k8 = *(const bf16x8*)&Gb[(long)nof[j] * 1024 + 512 + c];
#pragma unroll
      for (int e = 0; e < 8; ++e) lg[j] += qv[e] * (float)k8[e];
    }
#pragma unroll
    for (int e = 0; e < 8; ++e) {
      const float* sr = &srel[(c + e) * 3];
      rq[0] += qv[e] * sr[0];
      rq[1] += qv[e] * sr[1];
      rq[2] += qv[e] * sr[2];
    }
  }
#pragma unroll
  for (int j = 0; j < 9; ++j) red[ch][px][j] = lg[j] * msk[j];
#pragma unroll
  for (int l = 0; l < 3; ++l) red[ch][px][9 + l] = rq[l];
  __syncthreads();

  float a[9];
  float mx = -1e30f;
#pragma unroll
  for (int j = 0; j < 9; ++j) {
    float v = 0.f;
#pragma unroll
    for (int u = 0; u < 8; ++u) v += red[u][px][j];
    float qxl = red[0][px][9 + j % 3] + red[1][px][9 + j % 3] +
                red[2][px][9 + j % 3] + red[3][px][9 + j % 3];
    float qyk = red[4][px][9 + j / 3] + red[5][px][9 + j / 3] +
                red[6][px][9 + j / 3] + red[7][px][9 + j / 3];
    a[j] = v + qxl + qyk;
    mx = fmaxf(mx, a[j]);
  }
  float sum = 0.f;
#pragma unroll
  for (int j = 0; j < 9; ++j) { a[j] = __expf(a[j] - mx); sum += a[j]; }
  const float inv = 1.f / sum;
  float am[9];
#pragma unroll
  for (int j = 0; j < 9; ++j) am[j] = a[j] * inv * msk[j];

#pragma unroll
  for (int i = 0; i < 4; ++i) {
    const int c = c0 + i * 8;
    bf16x8 l28 = *(const bf16x8*)&Gb[(long)p * 1024 + 0 + c];
    float o8[8] = {0, 0, 0, 0, 0, 0, 0, 0};
#pragma unroll
    for (int j = 0; j < 9; ++j) {
      bf16x8 v8 = *(const bf16x8*)&Gb[(long)nof[j] * 1024 + 768 + c];
#pragma unroll
      for (int e = 0; e < 8; ++e) o8[e] += am[j] * (float)v8[e];
    }
#pragma unroll
    for (int e = 0; e < 8; ++e) {
      const int cg = c + e;
      localO[((long)b * C + cg) * NP + p] = f2bf_rne(
          (float)l28[e] * sS[cg] + sO[cg] + o8[e] + sBias[cg]);
    }
  }
}

// ---------------- FUSED: qkv GEMM ∥ local_attn, roles interleaved 3:2 ------
__global__ __launch_bounds__(256) void la_qkv(
    const unsigned short* __restrict__ Wqkv, const unsigned short* __restrict__ XT,
    unsigned short* __restrict__ GB, const unsigned short* __restrict__ GA,
    const float* __restrict__ rel_x, const float* __restrict__ rel_y,
    const float* __restrict__ bn2_g, const float* __restrict__ bn2_b,
    const float* __restrict__ bn2_m, const float* __restrict__ bn2_v,
    const float* __restrict__ l1_bias, unsigned short* __restrict__ localO)
{
  __shared__ __align__(16) char smem[19456];
  const int bx = blockIdx.x;             // 1440 = 288 groups of 5 (3 gemm+2 la)
  const int g = bx / 5, r = bx % 5;
  if (r < 3) {
    const int gi = g * 3 + r;            // 0..863
    const int n = gi % 72, rest = gi / 72;
    const int m = rest % 6, b = rest / 6;
    gemm_bt_body((unsigned short*)smem, Wqkv, XT + (long)b * NP * 256,
                 GB + (long)b * NP * 768, 768, m * 128, n * 128);
  } else {
    const int li = g * 2 + (r - 3);      // 0..575
    const int orig = li % 288, b = li / 288;
    // XCD-aware bijective swizzle (288 % 8 == 0)
    const int tile = (orig & 7) * 36 + (orig >> 3);
    local_attn_body(smem, GA, b, tile, rel_x, rel_y, bn2_g, bn2_b, bn2_m,
                    bn2_v, l1_bias, localO);
  }
}

// ---------------- bf16 GEMM, fp32 channel-major out, 64x128 tile (pw) ------
__global__ __launch_bounds__(256) void gemm_cf32(
    const unsigned short* __restrict__ W, const unsigned short* __restrict__ XT,
    float* __restrict__ Co)
{
  __shared__ unsigned short As[64][40];
  __shared__ unsigned short Bs[128][40];

  const int t = threadIdx.x;
  const int lane = t & 63, wid = t >> 6;
  const int wm = wid >> 1, wn = wid & 1;
  const int l15 = lane & 15, l4 = lane >> 4;
  const int n0 = blockIdx.x * 128, m0 = blockIdx.y * 64;
  const unsigned short* XTb = XT + (long)blockIdx.z * NP * 256;
  float* Cb = Co + (long)blockIdx.z * C * NP;

  f32x4 acc[2][4];
#pragma unroll
  for (int i = 0; i < 2; ++i)
#pragma unroll
    for (int j = 0; j < 4; ++j) acc[i][j] = (f32x4){0.f, 0.f, 0.f, 0.f};

  for (int k0 = 0; k0 < 256; k0 += 32) {
    {
      int r = t >> 2, kc = t & 3;
      *(uint4*)&As[r][kc * 8] =
          *(const uint4*)&W[(long)(m0 + r) * 256 + k0 + kc * 8];
    }
#pragma unroll
    for (int i = 0; i < 2; ++i) {
      int s = i * 256 + t, r = s >> 2, kc = s & 3;
      *(uint4*)&Bs[r][kc * 8] =
          *(const uint4*)&XTb[(long)(n0 + r) * 256 + k0 + kc * 8];
    }
    __syncthreads();

    bf16x8 af[2], bb[4];
#pragma unroll
    for (int mf = 0; mf < 2; ++mf)
      af[mf] = *(const bf16x8*)&As[wm * 32 + mf * 16 + l15][l4 * 8];
#pragma unroll
    for (int nf = 0; nf < 4; ++nf)
      bb[nf] = *(const bf16x8*)&Bs[wn * 64 + nf * 16 + l15][l4 * 8];
#pragma unroll
    for (int mf = 0; mf < 2; ++mf)
#pragma unroll
      for (int nf = 0; nf < 4; ++nf)
        acc[mf][nf] = __builtin_amdgcn_mfma_f32_16x16x32_bf16(
            af[mf], bb[nf], acc[mf][nf], 0, 0, 0);
    __syncthreads();
  }

#pragma unroll
  for (int mf = 0; mf < 2; ++mf)
#pragma unroll
    for (int r = 0; r < 4; ++r) {
      int row = m0 + wm * 32 + mf * 16 + l4 * 4 + r;
#pragma unroll
      for (int nf = 0; nf < 4; ++nf) {
        int col = n0 + wn * 64 + nf * 16 + l15;
        Cb[(long)row * NP + col] = acc[mf][nf][r];
      }
    }
}

// ---------------- 8x8 window attention via MFMA -> bf16 --------------------
__global__ __launch_bounds__(64) void window_attn_mfma(
    const unsigned short* __restrict__ QKV,
    const float* __restrict__ rel_table, unsigned short* __restrict__ attnO)
{
  const int win = blockIdx.x, hd = blockIdx.y, b = blockIdx.z;
  const int wy = win / 12, wx = win % 12;
  const int lane = threadIdx.x;
  const int l15 = lane & 15, hi4 = lane >> 4;
  const int l31 = lane & 31, hi2 = lane >> 5;

  __shared__ float srpb[225];
  __shared__ __bf16 P[64][72];

  for (int i = lane; i < 225; i += 64) srpb[i] = rel_table[i * 16 + hd];

  const __bf16* base = (const __bf16*)QKV + (long)b * 9216 * 768;
  const int pixbase = (wy * 8) * 96 + wx * 8;

#define WPIX(i) (pixbase + ((i) >> 3) * 96 + ((i) & 7))

  bf16x8 kf[2], qf[2];
#pragma unroll
  for (int kt = 0; kt < 2; ++kt)
    kf[kt] = *(const bf16x8*)&base[(long)WPIX(32 * kt + l31) * 768 + 256 +
                                   hd * 16 + hi2 * 8];
#pragma unroll
  for (int qt = 0; qt < 2; ++qt)
    qf[qt] = *(const bf16x8*)&base[(long)WPIX(32 * qt + l31) * 768 +
                                   hd * 16 + hi2 * 8];

  bf16x8 vf[2];
#pragma unroll
  for (int kc = 0; kc < 2; ++kc)
#pragma unroll
    for (int j = 0; j < 8; ++j)
      vf[kc][j] = base[(long)WPIX(32 * kc + 8 * hi4 + j) * 768 + 512 +
                       hd * 16 + l15];

  f32x16 S[2][2];
#pragma unroll
  for (int kt = 0; kt < 2; ++kt)
#pragma unroll
    for (int qt = 0; qt < 2; ++qt)
#pragma unroll
      for (int r = 0; r < 16; ++r) S[kt][qt][r] = 0.f;

#pragma unroll
  for (int kt = 0; kt < 2; ++kt)
#pragma unroll
    for (int qt = 0; qt < 2; ++qt)
      S[kt][qt] = __builtin_amdgcn_mfma_f32_32x32x16_bf16(
          kf[kt], qf[qt], S[kt][qt], 0, 0, 0);

  __syncthreads();

  float mx[2] = {-1e30f, -1e30f};
#pragma unroll
  for (int kt = 0; kt < 2; ++kt)
#pragma unroll
    for (int r = 0; r < 16; ++r) {
      const int key = 32 * kt + (r & 3) + 8 * (r >> 2) + 4 * hi2;
      const int ky = key >> 3, kx = key & 7;
#pragma unroll
      for (int qt = 0; qt < 2; ++qt) {
        const int q = 32 * qt + l31;
        const int qy = q >> 3, qx = q & 7;
        float s = S[kt][qt][r] * 0.25f + srpb[(qy - ky + 7) * 15 + (qx - kx + 7)];
        S[kt][qt][r] = s;
        mx[qt] = fmaxf(mx[qt], s);
      }
    }
#pragma unroll
  for (int qt = 0; qt < 2; ++qt)
    mx[qt] = fmaxf(mx[qt], __shfl_xor(mx[qt], 32));

  float sum[2] = {0.f, 0.f};
#pragma unroll
  for (int kt = 0; kt < 2; ++kt)
#pragma unroll
    for (int qt = 0; qt < 2; ++qt)
#pragma unroll
      for (int r = 0; r < 16; ++r) {
        float e = __expf(S[kt][qt][r] - mx[qt]);
        S[kt][qt][r] = e;
        sum[qt] += e;
      }
#pragma unroll
  for (int qt = 0; qt < 2; ++qt) sum[qt] += __shfl_xor(sum[qt], 32);
  const float inv0 = 1.f / sum[0], inv1 = 1.f / sum[1];

#pragma unroll
  for (int qt = 0; qt < 2; ++qt) {
    const float inv = qt ? inv1 : inv0;
#pragma unroll
    for (int kt = 0; kt < 2; ++kt)
#pragma unroll
      for (int rq = 0; rq < 4; ++rq) {
        bf16x4 pk;
#pragma unroll
        for (int j = 0; j < 4; ++j) pk[j] = f2bf16(S[kt][qt][rq * 4 + j] * inv);
        *(bf16x4*)&P[32 * qt + l31][32 * kt + 8 * rq + 4 * hi2] = pk;
      }
  }
  __syncthreads();

  f32x4 o[4];
#pragma unroll
  for (int qt4 = 0; qt4 < 4; ++qt4) o[qt4] = (f32x4){0.f, 0.f, 0.f, 0.f};
#pragma unroll
  for (int kc = 0; kc < 2; ++kc)
#pragma unroll
    for (int qt4 = 0; qt4 < 4; ++qt4) {
      bf16x8 pf = *(const bf16x8*)&P[16 * qt4 + l15][32 * kc + 8 * hi4];
      o[qt4] = __builtin_amdgcn_mfma_f32_16x16x32_bf16(vf[kc], pf, o[qt4], 0, 0, 0);
    }

#pragma unroll
  for (int qt4 = 0; qt4 < 4; ++qt4)
#pragma unroll
    for (int r = 0; r < 4; ++r) {
      const int q = 16 * qt4 + l15;
      attnO[((long)b * C + hd * 16 + 4 * hi4 + r) * NP + WPIX(q)] =
          f2bf_rne(o[qt4][r]);
    }
#undef WPIX
}

// ---------------- fused pools + combine + dw conv + BN -> bf16 out ---------
__global__ __launch_bounds__(128) void pool_dw8(
    const unsigned short* __restrict__ attn,
    const unsigned short* __restrict__ localO,
    const float* __restrict__ dww,
    const float* __restrict__ bnp_g, const float* __restrict__ bnp_b,
    const float* __restrict__ bnp_m, const float* __restrict__ bnp_v,
    unsigned short* __restrict__ dst)
{
  const int r0 = blockIdx.x * 12;
  const int c = blockIdx.y, b = blockIdx.z;
  const int t = threadIdx.x;

  __shared__ float img[26 * 116];
  __shared__ float img2[19 * 108];

  const unsigned short* A = attn + ((long)b * C + c) * NP;
  const unsigned short* L = localO + ((long)b * C + c) * NP;

  for (int idx = t; idx < 26 * 28; idx += 128) {
    const int j = idx / 28, k = idx % 28;
    const int R = r0 - 6 + j;
    const bool rv = (R >= 0 && R <= 96);
    const int Rc = (R == 96) ? 94 : (rv ? R : 0);
    const int s0 = 4 * k - 8;
    float4 v = {-1e30f, -1e30f, -1e30f, -1e30f};
    if (rv && s0 >= 0 && s0 <= 92) v = bf4_to_f4(&A[Rc * 96 + s0]);
    else if (rv && s0 == 96) v.x = bf2f(A[Rc * 96 + 94]);
    *(float4*)&img[j * 116 + 4 * k] = v;
  }
  for (int idx = t; idx < 19 * 27; idx += 128) {
    const int j2 = idx / 27, g = idx % 27;
    const int R2 = r0 - 3 + j2;
    const bool rv = (R2 >= 0 && R2 <= 96);
    const int R2c = (R2 == 96) ? 94 : (rv ? R2 : 0);
    const int w0 = 4 * g - 4;
    float4 v = {0.f, 0.f, 0.f, 0.f};
    if (rv) {
      if (w0 >= 0 && w0 <= 92) v = bf4_to_f4(&L[R2c * 96 + w0]);
      else if (w0 == 96) v.x = bf2f(L[R2c * 96 + 94]);
    }
    *(float4*)&img2[j2 * 108 + 4 * g] = v;
  }
  float wr[64];
#pragma unroll
  for (int i = 0; i < 64; ++i) wr[i] = dww[c * 64 + i];
  const float scl = bnp_g[c] * rsqrtf(bnp_v[c] + 1e-5f);
  const float off = bnp_b[c] - bnp_m[c] * scl;
  __syncthreads();

  const int j2lo = (r0 == 0) ? 3 : 0;
  const int j2hi = (r0 == 84) ? 14 : 18;
  if (t < 120) {
    const int blk = t / 24, G = t % 24;
    const int j2b = j2lo + blk * 4;
    if (j2b <= j2hi) {
      float4 hc[11];
#pragma unroll
      for (int ii = 0; ii < 11; ++ii) {
        int rr = j2b + ii;
        rr = (rr > 25) ? 25 : rr;
        hc[ii] = *(const float4*)&img[rr * 116 + 4 * G + 8];
      }
#pragma unroll
      for (int r = 0; r < 4; ++r) {
        const int j2 = j2b + r;
        if (j2 > j2hi) break;
        float mph[4] = {-1e30f, -1e30f, -1e30f, -1e30f};
        float aph[4] = {0.f, 0.f, 0.f, 0.f};
#pragma unroll
        for (int ii = 0; ii < 8; ++ii) {
          const float h4[4] = {hc[r + ii].x, hc[r + ii].y, hc[r + ii].z,
                               hc[r + ii].w};
#pragma unroll
          for (int d = 0; d < 4; ++d) {
            mph[d] = fmaxf(mph[d], h4[d]);
            aph[d] += (h4[d] > -1e29f) ? h4[d] : 0.f;
          }
        }
        float rw[12];
        {
          const float* row = &img[(j2 + 3) * 116 + 4 * G + 4];
          float4 a0 = *(const float4*)&row[0];
          float4 a1 = *(const float4*)&row[4];
          float4 a2 = *(const float4*)&row[8];
          rw[0] = a0.x; rw[1] = a0.y; rw[2] = a0.z; rw[3] = a0.w;
          rw[4] = a1.x; rw[5] = a1.y; rw[6] = a1.z; rw[7] = a1.w;
          rw[8] = a2.x; rw[9] = a2.y; rw[10] = a2.z; rw[11] = a2.w;
        }
        float4 lv = *(const float4*)&img2[j2 * 108 + 4 * G + 4];
        const float l4[4] = {lv.x, lv.y, lv.z, lv.w};
        float o4[4];
#pragma unroll
        for (int d = 0; d < 4; ++d) {
          float mpw = -1e30f, apw = 0.f;
#pragma unroll
          for (int ii = 0; ii < 8; ++ii) {
            const float wv = rw[d + 1 + ii];
            mpw = fmaxf(mpw, wv);
            apw += (wv > -1e29f) ? wv : 0.f;
          }
          o4[d] = mph[d] + mpw + (aph[d] + apw) * 0.125f + l4[d];
        }
        float4 out;
        out.x = o4[0]; out.y = o4[1]; out.z = o4[2]; out.w = o4[3];
        *(float4*)&img2[j2 * 108 + 4 * G + 4] = out;
        if (G == 23) img2[j2 * 108 + 100] = o4[2];
        if (r0 == 84 && j2 == 13) {
          *(float4*)&img2[15 * 108 + 4 * G + 4] = out;
          if (G == 23) img2[15 * 108 + 100] = o4[2];
        }
      }
    }
  }
  __syncthreads();

  if (t < 72) {
    const int cb = t / 24, ocg = t % 24;
    const int hh0 = cb * 4;
    float acc[4][4];
#pragma unroll
    for (int o = 0; o < 4; ++o)
#pragma unroll
      for (int d = 0; d < 4; ++d) acc[o][d] = 0.f;
#pragma unroll
    for (int i = 0; i < 11; ++i) {
      const float* row = &img2[(hh0 + i) * 108 + 4 * ocg];
      float w12[12];
      {
        float4 a0 = *(const float4*)&row[0];
        float4 a1 = *(const float4*)&row[4];
        float4 a2 = *(const float4*)&row[8];
        w12[0] = a0.x; w12[1] = a0.y; w12[2] = a0.z; w12[3] = a0.w;
        w12[4] = a1.x; w12[5] = a1.y; w12[6] = a1.z; w12[7] = a1.w;
        w12[8] = a2.x; w12[9] = a2.y; w12[10] = a2.z; w12[11] = a2.w;
      }
#pragma unroll
      for (int o = 0; o < 4; ++o) {
        if (o > i || i - o > 7) continue;
        const int ir = i - o;
#pragma unroll
        for (int d = 0; d < 4; ++d)
#pragma unroll
          for (int jj = 0; jj < 8; ++jj)
            acc[o][d] = fmaf(wr[ir * 8 + jj], w12[d + 1 + jj], acc[o][d]);
      }
    }
#pragma unroll
    for (int o = 0; o < 4; ++o) {
      unsigned short u4[4];
#pragma unroll
      for (int d = 0; d < 4; ++d) u4[d] = f2bf_rne(acc[o][d] * scl + off);
      *(uint2*)&dst[((long)b * C + c) * NP + (r0 + hh0 + o) * 96 + 4 * ocg] =
          *(const uint2*)u4;
    }
  }
}

}  // namespace

extern "C" void kernel_launch(void* const* d_in, const int* in_sizes, int n_in,
                              void* d_out, int out_size, void* d_ws, size_t ws_size,
                              hipStream_t stream) {
  const float* x         = (const float*)d_in[0];
  const float* qkv_w     = (const float*)d_in[1];
  const float* l2_w      = (const float*)d_in[2];
  const float* bn2_g     = (const float*)d_in[3];
  const float* bn2_b     = (const float*)d_in[4];
  const float* bn2_m     = (const float*)d_in[5];
  const float* bn2_v     = (const float*)d_in[6];
  const float* wq        = (const float*)d_in[7];
  const float* wk        = (const float*)d_in[8];
  const float* wv        = (const float*)d_in[9];
  const float* rel_x     = (const float*)d_in[10];
  const float* rel_y     = (const float*)d_in[11];
  const float* l1_bias   = (const float*)d_in[12];
  const float* rel_table = (const float*)d_in[13];
  const float* dw_w      = (const float*)d_in[14];
  const float* bnp_g     = (const float*)d_in[15];
  const float* bnp_b     = (const float*)d_in[16];
  const float* bnp_m     = (const float*)d_in[17];
  const float* bnp_v     = (const float*)d_in[18];
  const float* pw_w      = (const float*)d_in[19];
  float* out = (float*)d_out;
  float* ws  = (float*)d_ws;

  unsigned short* GA     = (unsigned short*)ws;                      // [0,9.44M)
  unsigned short* GB     = (unsigned short*)(ws + 9437184);          // 7.08M
  unsigned short* localB = (unsigned short*)(ws + 16515072);         // 2.36M
  unsigned short* W7     = (unsigned short*)(ws + 18874368);         // 0.26M
  unsigned short* XT     = (unsigned short*)(ws + 19136512);         // 2.36M
  unsigned short* attnB  = (unsigned short*)(ws + 19136512);         // alias XT
  unsigned short* dwB    = (unsigned short*)ws;                      // over GA
  unsigned short* XT2    = (unsigned short*)(ws + 4718592);          // over GA

  // 1. prep: weights -> W7 (blocks 0..2047) + x -> XT (blocks 2048..3199)
  prep<<<dim3(3200), 256, 0, stream>>>(x, l2_w, wq, wk, wv, qkv_w, pw_w,
                                       XT, W7);

  // 2. [l2|qL|kL|vL] -> GA bf16 [pix][1024]
  gemm_bt<<<dim3(72, 8, 2), 256, 0, stream>>>(W7, XT, GA, 1024);

  // 3. FUSED: qkv GEMM -> GB  ∥  neighborhood attention -> localB
  la_qkv<<<dim3(1440), 256, 0, stream>>>(W7 + 1024 * 256, XT, GB, GA,
                                         rel_x, rel_y, bn2_g, bn2_b, bn2_m,
                                         bn2_v, l1_bias, localB);

  // 4. window attention (MFMA) -> attnB (over dead XT)
  window_attn_mfma<<<dim3(144, 16, 2), 64, 0, stream>>>(GB, rel_table, attnB);

  // 5. pools + combine + depthwise conv + BN -> dwB bf16 (over dead GA)
  pool_dw8<<<dim3(8, 256, 2), 128, 0, stream>>>(attnB, localB, dw_w, bnp_g,
                                                bnp_b, bnp_m, bnp_v, dwB);

  // 6. dwB bf16 -> XT2 bf16 [pix][256]
  xpose_bf<<<dim3(144, 4, 2), 256, 0, stream>>>(dwB, XT2);

  // 7. pointwise GEMM -> out (fp32 channel-major, 64x128 tiles)
  gemm_cf32<<<dim3(72, 4, 2), 256, 0, stream>>>(W7 + 1792 * 256, XT2, out);
}

// Round 19
// 162.598 us; speedup vs baseline: 1.0435x; 1.0158x over previous
//
#include <hip/hip_runtime.h>
#include <math.h>

// GlobalLocalAttention — round 18: LOCK-IN of round-14 config (best measured,
// 162.8 µs). bf16-dwB experiment (R16/R17) reverted: netted negative/noise.
//
// Pipeline:
//  1. prep:    {x -> XT bf16}  ∪  {weights -> W7 bf16}
//  2. gemm_bt(W7[0:1024])    -> GA bf16 [b][NP][1024]
//  3. la_qkv:  {gemm qkv -> GB}  ∥  {local_attn(GA) -> localB}  (3:2 interleave)
//  4. window_attn_mfma(GB)   -> attnB bf16 (aliases XT, dead)
//  5. pool_dw8               -> dwB fp32 (over dead GA)
//  6. xpose(dwB)             -> XT2 bf16
//  7. gemm_cf32(W7[1792:2048], XT2) -> d_out

namespace {

constexpr int NP = 96 * 96;   // 9216
constexpr int C  = 256;

typedef __bf16 bf16x8 __attribute__((ext_vector_type(8)));
typedef __bf16 bf16x4 __attribute__((ext_vector_type(4)));
typedef float  f32x4  __attribute__((ext_vector_type(4)));
typedef float  f32x16 __attribute__((ext_vector_type(16)));

__device__ __forceinline__ unsigned short f2bf_rne(float f) {
  unsigned u = __float_as_uint(f);
  u += 0x7FFFu + ((u >> 16) & 1u);
  return (unsigned short)(u >> 16);
}
__device__ __forceinline__ __bf16 f2bf16(float f) {
  unsigned short s = f2bf_rne(f);
  return *(__bf16*)&s;
}
__device__ __forceinline__ float bf2f(unsigned short s) {
  unsigned u = (unsigned)s << 16;
  return __uint_as_float(u);
}
__device__ __forceinline__ float4 bf4_to_f4(const unsigned short* p) {
  bf16x4 v = *(const bf16x4*)p;
  float4 r;
  r.x = (float)v[0]; r.y = (float)v[1]; r.z = (float)v[2]; r.w = (float)v[3];
  return r;
}

// ---------------- merged prep: weight cvt (blocks 0..2047) + x transpose ----
__global__ __launch_bounds__(256) void prep(
    const float* __restrict__ x,
    const float* __restrict__ l2, const float* __restrict__ q,
    const float* __restrict__ k,  const float* __restrict__ v,
    const float* __restrict__ qkv, const float* __restrict__ pw,
    unsigned short* __restrict__ XT, unsigned short* __restrict__ W7)
{
  __shared__ float tile[64][65];
  const int bx = blockIdx.x;
  const int t = threadIdx.x;
  if (bx < 2048) {
    const int row = bx;
    const float* src; int r;
    if      (row <  256) { src = l2;  r = row; }
    else if (row <  512) { src = q;   r = row - 256; }
    else if (row <  768) { src = k;   r = row - 512; }
    else if (row < 1024) { src = v;   r = row - 768; }
    else if (row < 1792) { src = qkv; r = row - 1024; }
    else                 { src = pw;  r = row - 1792; }
    W7[row * 256 + t] = f2bf_rne(src[r * 256 + t]);
    return;
  }
  const int xb = bx - 2048;
  const int p0 = (xb % 144) * 64;
  const int c0 = ((xb / 144) % 4) * 64;
  const int b  = xb / 576;
  const float* xb_p = x + (long)b * C * NP;
#pragma unroll
  for (int i = 0; i < 4; ++i) {
    int s = i * 256 + t;
    int c = s >> 4, p4 = s & 15;
    float4 vv = *(const float4*)&xb_p[(long)(c0 + c) * NP + p0 + p4 * 4];
    tile[c][p4 * 4 + 0] = vv.x;
    tile[c][p4 * 4 + 1] = vv.y;
    tile[c][p4 * 4 + 2] = vv.z;
    tile[c][p4 * 4 + 3] = vv.w;
  }
  __syncthreads();
  unsigned short* XTb = XT + (long)b * NP * 256;
#pragma unroll
  for (int i = 0; i < 2; ++i) {
    int s = i * 256 + t;
    int p = s >> 3, c8 = s & 7;
    unsigned short u[8];
#pragma unroll
    for (int e = 0; e < 8; ++e) u[e] = f2bf_rne(tile[c8 * 8 + e][p]);
    *(uint4*)&XTb[(long)(p0 + p) * 256 + c0 + c8 * 8] = *(const uint4*)u;
  }
}

// ---------------- transpose: fp32 [c][pix] -> bf16 [pix][c] (dwB -> XT2) ---
__global__ __launch_bounds__(256) void xpose(
    const float* __restrict__ x, unsigned short* __restrict__ XT)
{
  __shared__ float tile[64][65];
  const int t = threadIdx.x;
  const int p0 = blockIdx.x * 64, c0 = blockIdx.y * 64, b = blockIdx.z;
  const float* xb = x + (long)b * C * NP;
#pragma unroll
  for (int i = 0; i < 4; ++i) {
    int s = i * 256 + t;
    int c = s >> 4, p4 = s & 15;
    float4 v = *(const float4*)&xb[(long)(c0 + c) * NP + p0 + p4 * 4];
    tile[c][p4 * 4 + 0] = v.x;
    tile[c][p4 * 4 + 1] = v.y;
    tile[c][p4 * 4 + 2] = v.z;
    tile[c][p4 * 4 + 3] = v.w;
  }
  __syncthreads();
  unsigned short* XTb = XT + (long)b * NP * 256;
#pragma unroll
  for (int i = 0; i < 2; ++i) {
    int s = i * 256 + t;
    int p = s >> 3, c8 = s & 7;
    unsigned short u[8];
#pragma unroll
    for (int e = 0; e < 8; ++e) u[e] = f2bf_rne(tile[c8 * 8 + e][p]);
    *(uint4*)&XTb[(long)(p0 + p) * 256 + c0 + c8 * 8] = *(const uint4*)u;
  }
}

// ---------------- gemm tile body (gll staging; 2-pass within-wave epilogue) -
__device__ __forceinline__ void gemm_bt_body(
    unsigned short* smemS,
    const unsigned short* __restrict__ W, const unsigned short* __restrict__ XTb,
    unsigned short* __restrict__ Ob, int Mstride, int m0, int n0)
{
  unsigned short* As = smemS;            // [128][32] linear
  unsigned short* Bs = smemS + 4096;     // [128][32] linear

  const int t = threadIdx.x;
  const int lane = t & 63, wid = t >> 6;
  const int wm = wid >> 1, wn = wid & 1;
  const int l15 = lane & 15, l4 = lane >> 4;
  const int crow = lane >> 2;
  const int ccol = (lane & 3) * 8;

  f32x4 acc[4][4];
#pragma unroll
  for (int i = 0; i < 4; ++i)
#pragma unroll
    for (int j = 0; j < 4; ++j) acc[i][j] = (f32x4){0.f, 0.f, 0.f, 0.f};

  for (int k0 = 0; k0 < 256; k0 += 32) {
#pragma unroll
    for (int i = 0; i < 4; ++i) {
      const int ch = wid * 4 + i;
      if (ch < 8) {
        const int row = ch * 16 + crow;
        __builtin_amdgcn_global_load_lds(
            (const __attribute__((address_space(1))) unsigned int*)
                &W[(long)(m0 + row) * 256 + k0 + ccol],
            (__attribute__((address_space(3))) unsigned int*)&As[ch * 512],
            16, 0, 0);
      } else {
        const int row = (ch - 8) * 16 + crow;
        __builtin_amdgcn_global_load_lds(
            (const __attribute__((address_space(1))) unsigned int*)
                &XTb[(long)(n0 + row) * 256 + k0 + ccol],
            (__attribute__((address_space(3))) unsigned int*)&Bs[(ch - 8) * 512],
            16, 0, 0);
      }
    }
    __syncthreads();

    bf16x8 af[4], bb[4];
#pragma unroll
    for (int mf = 0; mf < 4; ++mf)
      af[mf] = *(const bf16x8*)&As[(wm * 64 + mf * 16 + l15) * 32 + l4 * 8];
#pragma unroll
    for (int nf = 0; nf < 4; ++nf)
      bb[nf] = *(const bf16x8*)&Bs[(wn * 64 + nf * 16 + l15) * 32 + l4 * 8];
#pragma unroll
    for (int mf = 0; mf < 4; ++mf)
#pragma unroll
      for (int nf = 0; nf < 4; ++nf)
        acc[mf][nf] = __builtin_amdgcn_mfma_f32_16x16x32_bf16(
            af[mf], bb[nf], acc[mf][nf], 0, 0, 0);
    __syncthreads();
  }

  // Epilogue: per-wave 32x72 region; within-wave only, no barriers.
  unsigned short* trw = smemS + wid * 2304;      // 32 * 72 shorts
  const int lp = lane >> 1;                      // local pixel 0..31
  const int cbase = (lane & 1) * 4;              // 4 chunks of 16B each
#pragma unroll
  for (int pass = 0; pass < 2; ++pass) {
#pragma unroll
    for (int nfh = 0; nfh < 2; ++nfh) {
      const int nf = pass * 2 + nfh;
#pragma unroll
      for (int mf = 0; mf < 4; ++mf) {
        unsigned u0 = (unsigned)f2bf_rne(acc[mf][nf][0]) |
                      ((unsigned)f2bf_rne(acc[mf][nf][1]) << 16);
        unsigned u1 = (unsigned)f2bf_rne(acc[mf][nf][2]) |
                      ((unsigned)f2bf_rne(acc[mf][nf][3]) << 16);
        uint2 uu; uu.x = u0; uu.y = u1;
        *(uint2*)&trw[(nfh * 16 + l15) * 72 + mf * 16 + l4 * 4] = uu;
      }
    }
    const long pix = n0 + wn * 64 + pass * 32 + lp;
    const long rowbase = pix * Mstride + m0 + wm * 64;
#pragma unroll
    for (int cc = 0; cc < 4; ++cc)
      *(uint4*)&Ob[rowbase + (cbase + cc) * 8] =
          *(const uint4*)&trw[lp * 72 + (cbase + cc) * 8];
  }
}

// ---------------- step-2 GEMM: A-phase [l2|qL|kL|vL] ------------------------
__global__ __launch_bounds__(256) void gemm_bt(
    const unsigned short* __restrict__ W, const unsigned short* __restrict__ XT,
    unsigned short* __restrict__ O, int Mstride)
{
  __shared__ __align__(16) unsigned short smemS[9216];   // 18,432 B
  gemm_bt_body(smemS, W, XT + (long)blockIdx.z * NP * 256,
               O + (long)blockIdx.z * NP * Mstride, Mstride,
               blockIdx.y * 128, blockIdx.x * 128);
}

// ---------------- local_attn body: 2D 8x4 pixel tile ------------------------
__device__ __forceinline__ void local_attn_body(
    char* smem,
    const unsigned short* __restrict__ GA, int b, int tile,
    const float* __restrict__ rel_x, const float* __restrict__ rel_y,
    const float* __restrict__ bn2_g, const float* __restrict__ bn2_b,
    const float* __restrict__ bn2_m, const float* __restrict__ bn2_v,
    const float* __restrict__ l1_bias, unsigned short* __restrict__ localO)
{
  float (*red)[32][13] = reinterpret_cast<float(*)[32][13]>(smem);   // 13312 B
  float* srel  = (float*)(smem + 13312);                             // 3072 B
  float* sS    = (float*)(smem + 16384);
  float* sO    = sS + 256;
  float* sBias = sO + 256;

  const int t = threadIdx.x;
  const int px = t & 31, ch = t >> 5;
  const int ty = tile / 24, tx = tile % 24;
  const int h = ty * 8 + (px >> 2), w = tx * 4 + (px & 3);
  const int p = h * 96 + w;
  const unsigned short* Gb = GA + (long)b * NP * 1024;

  if (t < 128) {
    srel[t * 3 + 0] = rel_x[t * 3 + 0];
    srel[t * 3 + 1] = rel_x[t * 3 + 1];
    srel[t * 3 + 2] = rel_x[t * 3 + 2];
  } else {
    int r = t - 128;
    srel[t * 3 + 0] = rel_y[r * 3 + 0];
    srel[t * 3 + 1] = rel_y[r * 3 + 1];
    srel[t * 3 + 2] = rel_y[r * 3 + 2];
  }
  {
    float s = bn2_g[t] * rsqrtf(bn2_v[t] + 1e-5f);
    sS[t] = s;
    sO[t] = bn2_b[t] - bn2_m[t] * s;
    sBias[t] = l1_bias[t];
  }

  int nof[9];
  float msk[9];
#pragma unroll
  for (int ky = 0; ky < 3; ++ky)
#pragma unroll
    for (int kx = 0; kx < 3; ++kx) {
      int j = ky * 3 + kx, hn = h + ky - 1, wn = w + kx - 1;
      bool v = (hn >= 0 && hn < 96 && wn >= 0 && wn < 96);
      nof[j] = v ? hn * 96 + wn : p;
      msk[j] = v ? 1.f : 0.f;
    }
  __syncthreads();

  float lg[9] = {0, 0, 0, 0, 0, 0, 0, 0, 0};
  float rq[3] = {0, 0, 0};
  const int c0 = ch * 32;
#pragma unroll
  for (int i = 0; i < 4; ++i) {
    const int c = c0 + i * 8;
    bf16x8 q8 = *(const bf16x8*)&Gb[(long)p * 1024 + 256 + c];
    float qv[8];
#pragma unroll
    for (int e = 0; e < 8; ++e) qv[e] = (float)q8[e];
#pragma unroll
    for (int j = 0; j < 9; ++j) {
      bf16x8 k8 = *(const bf16x8*)&Gb[(long)nof[j] * 1024 + 512 + c];
#pragma unroll
      for (int e = 0; e < 8; ++e) lg[j] += qv[e] * (float)k8[e];
    }
#pragma unroll
    for (int e = 0; e < 8; ++e) {
      const float* sr = &srel[(c + e) * 3];
      rq[0] += qv[e] * sr[0];
      rq[1] += qv[e] * sr[1];
      rq[2] += qv[e] * sr[2];
    }
  }
#pragma unroll
  for (int j = 0; j < 9; ++j) red[ch][px][j] = lg[j] * msk[j];
#pragma unroll
  for (int l = 0; l < 3; ++l) red[ch][px][9 + l] = rq[l];
  __syncthreads();

  float a[9];
  float mx = -1e30f;
#pragma unroll
  for (int j = 0; j < 9; ++j) {
    float v = 0.f;
#pragma unroll
    for (int u = 0; u < 8; ++u) v += red[u][px][j];
    float qxl = red[0][px][9 + j % 3] + red[1][px][9 + j % 3] +
                red[2][px][9 + j % 3] + red[3][px][9 + j % 3];
    float qyk = red[4][px][9 + j / 3] + red[5][px][9 + j / 3] +
                red[6][px][9 + j / 3] + red[7][px][9 + j / 3];
    a[j] = v + qxl + qyk;
    mx = fmaxf(mx, a[j]);
  }
  float sum = 0.f;
#pragma unroll
  for (int j = 0; j < 9; ++j) { a[j] = __expf(a[j] - mx); sum += a[j]; }
  const float inv = 1.f / sum;
  float am[9];
#pragma unroll
  for (int j = 0; j < 9; ++j) am[j] = a[j] * inv * msk[j];

#pragma unroll
  for (int i = 0; i < 4; ++i) {
    const int c = c0 + i * 8;
    bf16x8 l28 = *(const bf16x8*)&Gb[(long)p * 1024 + 0 + c];
    float o8[8] = {0, 0, 0, 0, 0, 0, 0, 0};
#pragma unroll
    for (int j = 0; j < 9; ++j) {
      bf16x8 v8 = *(const bf16x8*)&Gb[(long)nof[j] * 1024 + 768 + c];
#pragma unroll
      for (int e = 0; e < 8; ++e) o8[e] += am[j] * (float)v8[e];
    }
#pragma unroll
    for (int e = 0; e < 8; ++e) {
      const int cg = c + e;
      localO[((long)b * C + cg) * NP + p] = f2bf_rne(
          (float)l28[e] * sS[cg] + sO[cg] + o8[e] + sBias[cg]);
    }
  }
}

// ---------------- FUSED: qkv GEMM ∥ local_attn, roles interleaved 3:2 ------
__global__ __launch_bounds__(256) void la_qkv(
    const unsigned short* __restrict__ Wqkv, const unsigned short* __restrict__ XT,
    unsigned short* __restrict__ GB, const unsigned short* __restrict__ GA,
    const float* __restrict__ rel_x, const float* __restrict__ rel_y,
    const float* __restrict__ bn2_g, const float* __restrict__ bn2_b,
    const float* __restrict__ bn2_m, const float* __restrict__ bn2_v,
    const float* __restrict__ l1_bias, unsigned short* __restrict__ localO)
{
  __shared__ __align__(16) char smem[19456];
  const int bx = blockIdx.x;             // 1440 = 288 groups of 5 (3 gemm+2 la)
  const int g = bx / 5, r = bx % 5;
  if (r < 3) {
    const int gi = g * 3 + r;            // 0..863
    const int n = gi % 72, rest = gi / 72;
    const int m = rest % 6, b = rest / 6;
    gemm_bt_body((unsigned short*)smem, Wqkv, XT + (long)b * NP * 256,
                 GB + (long)b * NP * 768, 768, m * 128, n * 128);
  } else {
    const int li = g * 2 + (r - 3);      // 0..575
    const int orig = li % 288, b = li / 288;
    // XCD-aware bijective swizzle (288 % 8 == 0)
    const int tile = (orig & 7) * 36 + (orig >> 3);
    local_attn_body(smem, GA, b, tile, rel_x, rel_y, bn2_g, bn2_b, bn2_m,
                    bn2_v, l1_bias, localO);
  }
}

// ---------------- bf16 GEMM, fp32 channel-major out, 64x128 tile (pw) ------
__global__ __launch_bounds__(256) void gemm_cf32(
    const unsigned short* __restrict__ W, const unsigned short* __restrict__ XT,
    float* __restrict__ Co)
{
  __shared__ unsigned short As[64][40];
  __shared__ unsigned short Bs[128][40];

  const int t = threadIdx.x;
  const int lane = t & 63, wid = t >> 6;
  const int wm = wid >> 1, wn = wid & 1;
  const int l15 = lane & 15, l4 = lane >> 4;
  const int n0 = blockIdx.x * 128, m0 = blockIdx.y * 64;
  const unsigned short* XTb = XT + (long)blockIdx.z * NP * 256;
  float* Cb = Co + (long)blockIdx.z * C * NP;

  f32x4 acc[2][4];
#pragma unroll
  for (int i = 0; i < 2; ++i)
#pragma unroll
    for (int j = 0; j < 4; ++j) acc[i][j] = (f32x4){0.f, 0.f, 0.f, 0.f};

  for (int k0 = 0; k0 < 256; k0 += 32) {
    {
      int r = t >> 2, kc = t & 3;
      *(uint4*)&As[r][kc * 8] =
          *(const uint4*)&W[(long)(m0 + r) * 256 + k0 + kc * 8];
    }
#pragma unroll
    for (int i = 0; i < 2; ++i) {
      int s = i * 256 + t, r = s >> 2, kc = s & 3;
      *(uint4*)&Bs[r][kc * 8] =
          *(const uint4*)&XTb[(long)(n0 + r) * 256 + k0 + kc * 8];
    }
    __syncthreads();

    bf16x8 af[2], bb[4];
#pragma unroll
    for (int mf = 0; mf < 2; ++mf)
      af[mf] = *(const bf16x8*)&As[wm * 32 + mf * 16 + l15][l4 * 8];
#pragma unroll
    for (int nf = 0; nf < 4; ++nf)
      bb[nf] = *(const bf16x8*)&Bs[wn * 64 + nf * 16 + l15][l4 * 8];
#pragma unroll
    for (int mf = 0; mf < 2; ++mf)
#pragma unroll
      for (int nf = 0; nf < 4; ++nf)
        acc[mf][nf] = __builtin_amdgcn_mfma_f32_16x16x32_bf16(
            af[mf], bb[nf], acc[mf][nf], 0, 0, 0);
    __syncthreads();
  }

#pragma unroll
  for (int mf = 0; mf < 2; ++mf)
#pragma unroll
    for (int r = 0; r < 4; ++r) {
      int row = m0 + wm * 32 + mf * 16 + l4 * 4 + r;
#pragma unroll
      for (int nf = 0; nf < 4; ++nf) {
        int col = n0 + wn * 64 + nf * 16 + l15;
        Cb[(long)row * NP + col] = acc[mf][nf][r];
      }
    }
}

// ---------------- 8x8 window attention via MFMA -> bf16 --------------------
__global__ __launch_bounds__(64) void window_attn_mfma(
    const unsigned short* __restrict__ QKV,
    const float* __restrict__ rel_table, unsigned short* __restrict__ attnO)
{
  const int win = blockIdx.x, hd = blockIdx.y, b = blockIdx.z;
  const int wy = win / 12, wx = win % 12;
  const int lane = threadIdx.x;
  const int l15 = lane & 15, hi4 = lane >> 4;
  const int l31 = lane & 31, hi2 = lane >> 5;

  __shared__ float srpb[225];
  __shared__ __bf16 P[64][72];

  for (int i = lane; i < 225; i += 64) srpb[i] = rel_table[i * 16 + hd];

  const __bf16* base = (const __bf16*)QKV + (long)b * 9216 * 768;
  const int pixbase = (wy * 8) * 96 + wx * 8;

#define WPIX(i) (pixbase + ((i) >> 3) * 96 + ((i) & 7))

  bf16x8 kf[2], qf[2];
#pragma unroll
  for (int kt = 0; kt < 2; ++kt)
    kf[kt] = *(const bf16x8*)&base[(long)WPIX(32 * kt + l31) * 768 + 256 +
                                   hd * 16 + hi2 * 8];
#pragma unroll
  for (int qt = 0; qt < 2; ++qt)
    qf[qt] = *(const bf16x8*)&base[(long)WPIX(32 * qt + l31) * 768 +
                                   hd * 16 + hi2 * 8];

  bf16x8 vf[2];
#pragma unroll
  for (int kc = 0; kc < 2; ++kc)
#pragma unroll
    for (int j = 0; j < 8; ++j)
      vf[kc][j] = base[(long)WPIX(32 * kc + 8 * hi4 + j) * 768 + 512 +
                       hd * 16 + l15];

  f32x16 S[2][2];
#pragma unroll
  for (int kt = 0; kt < 2; ++kt)
#pragma unroll
    for (int qt = 0; qt < 2; ++qt)
#pragma unroll
      for (int r = 0; r < 16; ++r) S[kt][qt][r] = 0.f;

#pragma unroll
  for (int kt = 0; kt < 2; ++kt)
#pragma unroll
    for (int qt = 0; qt < 2; ++qt)
      S[kt][qt] = __builtin_amdgcn_mfma_f32_32x32x16_bf16(
          kf[kt], qf[qt], S[kt][qt], 0, 0, 0);

  __syncthreads();

  float mx[2] = {-1e30f, -1e30f};
#pragma unroll
  for (int kt = 0; kt < 2; ++kt)
#pragma unroll
    for (int r = 0; r < 16; ++r) {
      const int key = 32 * kt + (r & 3) + 8 * (r >> 2) + 4 * hi2;
      const int ky = key >> 3, kx = key & 7;
#pragma unroll
      for (int qt = 0; qt < 2; ++qt) {
        const int q = 32 * qt + l31;
        const int qy = q >> 3, qx = q & 7;
        float s = S[kt][qt][r] * 0.25f + srpb[(qy - ky + 7) * 15 + (qx - kx + 7)];
        S[kt][qt][r] = s;
        mx[qt] = fmaxf(mx[qt], s);
      }
    }
#pragma unroll
  for (int qt = 0; qt < 2; ++qt)
    mx[qt] = fmaxf(mx[qt], __shfl_xor(mx[qt], 32));

  float sum[2] = {0.f, 0.f};
#pragma unroll
  for (int kt = 0; kt < 2; ++kt)
#pragma unroll
    for (int qt = 0; qt < 2; ++qt)
#pragma unroll
      for (int r = 0; r < 16; ++r) {
        float e = __expf(S[kt][qt][r] - mx[qt]);
        S[kt][qt][r] = e;
        sum[qt] += e;
      }
#pragma unroll
  for (int qt = 0; qt < 2; ++qt) sum[qt] += __shfl_xor(sum[qt], 32);
  const float inv0 = 1.f / sum[0], inv1 = 1.f / sum[1];

#pragma unroll
  for (int qt = 0; qt < 2; ++qt) {
    const float inv = qt ? inv1 : inv0;
#pragma unroll
    for (int kt = 0; kt < 2; ++kt)
#pragma unroll
      for (int rq = 0; rq < 4; ++rq) {
        bf16x4 pk;
#pragma unroll
        for (int j = 0; j < 4; ++j) pk[j] = f2bf16(S[kt][qt][rq * 4 + j] * inv);
        *(bf16x4*)&P[32 * qt + l31][32 * kt + 8 * rq + 4 * hi2] = pk;
      }
  }
  __syncthreads();

  f32x4 o[4];
#pragma unroll
  for (int qt4 = 0; qt4 < 4; ++qt4) o[qt4] = (f32x4){0.f, 0.f, 0.f, 0.f};
#pragma unroll
  for (int kc = 0; kc < 2; ++kc)
#pragma unroll
    for (int qt4 = 0; qt4 < 4; ++qt4) {
      bf16x8 pf = *(const bf16x8*)&P[16 * qt4 + l15][32 * kc + 8 * hi4];
      o[qt4] = __builtin_amdgcn_mfma_f32_16x16x32_bf16(vf[kc], pf, o[qt4], 0, 0, 0);
    }

#pragma unroll
  for (int qt4 = 0; qt4 < 4; ++qt4)
#pragma unroll
    for (int r = 0; r < 4; ++r) {
      const int q = 16 * qt4 + l15;
      attnO[((long)b * C + hd * 16 + 4 * hi4 + r) * NP + WPIX(q)] =
          f2bf_rne(o[qt4][r]);
    }
#undef WPIX
}

// ---------------- fused pools + combine + dw conv + BN (conflict-free f4) --
__global__ __launch_bounds__(128) void pool_dw8(
    const unsigned short* __restrict__ attn,
    const unsigned short* __restrict__ localO,
    const float* __restrict__ dww,
    const float* __restrict__ bnp_g, const float* __restrict__ bnp_b,
    const float* __restrict__ bnp_m, const float* __restrict__ bnp_v,
    float* __restrict__ dst)
{
  const int r0 = blockIdx.x * 12;
  const int c = blockIdx.y, b = blockIdx.z;
  const int t = threadIdx.x;

  __shared__ float img[26 * 116];
  __shared__ float img2[19 * 108];

  const unsigned short* A = attn + ((long)b * C + c) * NP;
  const unsigned short* L = localO + ((long)b * C + c) * NP;

  for (int idx = t; idx < 26 * 28; idx += 128) {
    const int j = idx / 28, k = idx % 28;
    const int R = r0 - 6 + j;
    const bool rv = (R >= 0 && R <= 96);
    const int Rc = (R == 96) ? 94 : (rv ? R : 0);
    const int s0 = 4 * k - 8;
    float4 v = {-1e30f, -1e30f, -1e30f, -1e30f};
    if (rv && s0 >= 0 && s0 <= 92) v = bf4_to_f4(&A[Rc * 96 + s0]);
    else if (rv && s0 == 96) v.x = bf2f(A[Rc * 96 + 94]);
    *(float4*)&img[j * 116 + 4 * k] = v;
  }
  for (int idx = t; idx < 19 * 27; idx += 128) {
    const int j2 = idx / 27, g = idx % 27;
    const int R2 = r0 - 3 + j2;
    const bool rv = (R2 >= 0 && R2 <= 96);
    const int R2c = (R2 == 96) ? 94 : (rv ? R2 : 0);
    const int w0 = 4 * g - 4;
    float4 v = {0.f, 0.f, 0.f, 0.f};
    if (rv) {
      if (w0 >= 0 && w0 <= 92) v = bf4_to_f4(&L[R2c * 96 + w0]);
      else if (w0 == 96) v.x = bf2f(L[R2c * 96 + 94]);
    }
    *(float4*)&img2[j2 * 108 + 4 * g] = v;
  }
  float wr[64];
#pragma unroll
  for (int i = 0; i < 64; ++i) wr[i] = dww[c * 64 + i];
  const float scl = bnp_g[c] * rsqrtf(bnp_v[c] + 1e-5f);
  const float off = bnp_b[c] - bnp_m[c] * scl;
  __syncthreads();

  const int j2lo = (r0 == 0) ? 3 : 0;
  const int j2hi = (r0 == 84) ? 14 : 18;
  if (t < 120) {
    const int blk = t / 24, G = t % 24;
    const int j2b = j2lo + blk * 4;
    if (j2b <= j2hi) {
      float4 hc[11];
#pragma unroll
      for (int ii = 0; ii < 11; ++ii) {
        int rr = j2b + ii;
        rr = (rr > 25) ? 25 : rr;
        hc[ii] = *(const float4*)&img[rr * 116 + 4 * G + 8];
      }
#pragma unroll
      for (int r = 0; r < 4; ++r) {
        const int j2 = j2b + r;
        if (j2 > j2hi) break;
        float mph[4] = {-1e30f, -1e30f, -1e30f, -1e30f};
        float aph[4] = {0.f, 0.f, 0.f, 0.f};
#pragma unroll
        for (int ii = 0; ii < 8; ++ii) {
          const float h4[4] = {hc[r + ii].x, hc[r + ii].y, hc[r + ii].z,
                               hc[r + ii].w};
#pragma unroll
          for (int d = 0; d < 4; ++d) {
            mph[d] = fmaxf(mph[d], h4[d]);
            aph[d] += (h4[d] > -1e29f) ? h4[d] : 0.f;
          }
        }
        float rw[12];
        {
          const float* row = &img[(j2 + 3) * 116 + 4 * G + 4];
          float4 a0 = *(const float4*)&row[0];
          float4 a1 = *(const float4*)&row[4];
          float4 a2 = *(const float4*)&row[8];
          rw[0] = a0.x; rw[1] = a0.y; rw[2] = a0.z; rw[3] = a0.w;
          rw[4] = a1.x; rw[5] = a1.y; rw[6] = a1.z; rw[7] = a1.w;
          rw[8] = a2.x; rw[9] = a2.y; rw[10] = a2.z; rw[11] = a2.w;
        }
        float4 lv = *(const float4*)&img2[j2 * 108 + 4 * G + 4];
        const float l4[4] = {lv.x, lv.y, lv.z, lv.w};
        float o4[4];
#pragma unroll
        for (int d = 0; d < 4; ++d) {
          float mpw = -1e30f, apw = 0.f;
#pragma unroll
          for (int ii = 0; ii < 8; ++ii) {
            const float wv = rw[d + 1 + ii];
            mpw = fmaxf(mpw, wv);
            apw += (wv > -1e29f) ? wv : 0.f;
          }
          o4[d] = mph[d] + mpw + (aph[d] + apw) * 0.125f + l4[d];
        }
        float4 out;
        out.x = o4[0]; out.y = o4[1]; out.z = o4[2]; out.w = o4[3];
        *(float4*)&img2[j2 * 108 + 4 * G + 4] = out;
        if (G == 23) img2[j2 * 108 + 100] = o4[2];
        if (r0 == 84 && j2 == 13) {
          *(float4*)&img2[15 * 108 + 4 * G + 4] = out;
          if (G == 23) img2[15 * 108 + 100] = o4[2];
        }
      }
    }
  }
  __syncthreads();

  if (t < 72) {
    const int cb = t / 24, ocg = t % 24;
    const int hh0 = cb * 4;
    float acc[4][4];
#pragma unroll
    for (int o = 0; o < 4; ++o)
#pragma unroll
      for (int d = 0; d < 4; ++d) acc[o][d] = 0.f;
#pragma unroll
    for (int i = 0; i < 11; ++i) {
      const float* row = &img2[(hh0 + i) * 108 + 4 * ocg];
      float w12[12];
      {
        float4 a0 = *(const float4*)&row[0];
        float4 a1 = *(const float4*)&row[4];
        float4 a2 = *(const float4*)&row[8];
        w12[0] = a0.x; w12[1] = a0.y; w12[2] = a0.z; w12[3] = a0.w;
        w12[4] = a1.x; w12[5] = a1.y; w12[6] = a1.z; w12[7] = a1.w;
        w12[8] = a2.x; w12[9] = a2.y; w12[10] = a2.z; w12[11] = a2.w;
      }
#pragma unroll
      for (int o = 0; o < 4; ++o) {
        if (o > i || i - o > 7) continue;
        const int ir = i - o;
#pragma unroll
        for (int d = 0; d < 4; ++d)
#pragma unroll
          for (int jj = 0; jj < 8; ++jj)
            acc[o][d] = fmaf(wr[ir * 8 + jj], w12[d + 1 + jj], acc[o][d]);
      }
    }
#pragma unroll
    for (int o = 0; o < 4; ++o) {
      float4 s;
      s.x = acc[o][0] * scl + off;
      s.y = acc[o][1] * scl + off;
      s.z = acc[o][2] * scl + off;
      s.w = acc[o][3] * scl + off;
      *(float4*)&dst[((long)b * C + c) * NP + (r0 + hh0 + o) * 96 + 4 * ocg] = s;
    }
  }
}

}  // namespace

extern "C" void kernel_launch(void* const* d_in, const int* in_sizes, int n_in,
                              void* d_out, int out_size, void* d_ws, size_t ws_size,
                              hipStream_t stream) {
  const float* x         = (const float*)d_in[0];
  const float* qkv_w     = (const float*)d_in[1];
  const float* l2_w      = (const float*)d_in[2];
  const float* bn2_g     = (const float*)d_in[3];
  const float* bn2_b     = (const float*)d_in[4];
  const float* bn2_m     = (const float*)d_in[5];
  const float* bn2_v     = (const float*)d_in[6];
  const float* wq        = (const float*)d_in[7];
  const float* wk        = (const float*)d_in[8];
  const float* wv        = (const float*)d_in[9];
  const float* rel_x     = (const float*)d_in[10];
  const float* rel_y     = (const float*)d_in[11];
  const float* l1_bias   = (const float*)d_in[12];
  const float* rel_table = (const float*)d_in[13];
  const float* dw_w      = (const float*)d_in[14];
  const float* bnp_g     = (const float*)d_in[15];
  const float* bnp_b     = (const float*)d_in[16];
  const float* bnp_m     = (const float*)d_in[17];
  const float* bnp_v     = (const float*)d_in[18];
  const float* pw_w      = (const float*)d_in[19];
  float* out = (float*)d_out;
  float* ws  = (float*)d_ws;

  unsigned short* GA     = (unsigned short*)ws;                      // [0,9.44M)
  unsigned short* GB     = (unsigned short*)(ws + 9437184);          // 7.08M
  unsigned short* localB = (unsigned short*)(ws + 16515072);         // 2.36M
  unsigned short* W7     = (unsigned short*)(ws + 18874368);         // 0.26M
  unsigned short* XT     = (unsigned short*)(ws + 19136512);         // 2.36M
  unsigned short* attnB  = (unsigned short*)(ws + 19136512);         // alias XT
  float*          dwB    = ws;                                       // over GA
  unsigned short* XT2    = (unsigned short*)(ws + 4718592);          // over GA

  // 1. prep: weights -> W7 (blocks 0..2047) + x -> XT (blocks 2048..3199)
  prep<<<dim3(3200), 256, 0, stream>>>(x, l2_w, wq, wk, wv, qkv_w, pw_w,
                                       XT, W7);

  // 2. [l2|qL|kL|vL] -> GA bf16 [pix][1024]
  gemm_bt<<<dim3(72, 8, 2), 256, 0, stream>>>(W7, XT, GA, 1024);

  // 3. FUSED: qkv GEMM -> GB  ∥  neighborhood attention -> localB
  la_qkv<<<dim3(1440), 256, 0, stream>>>(W7 + 1024 * 256, XT, GB, GA,
                                         rel_x, rel_y, bn2_g, bn2_b, bn2_m,
                                         bn2_v, l1_bias, localB);

  // 4. window attention (MFMA) -> attnB (over dead XT)
  window_attn_mfma<<<dim3(144, 16, 2), 64, 0, stream>>>(GB, rel_table, attnB);

  // 5. pools + combine + depthwise conv + BN -> dwB (over dead GA)
  pool_dw8<<<dim3(8, 256, 2), 128, 0, stream>>>(attnB, localB, dw_w, bnp_g,
                                                bnp_b, bnp_m, bnp_v, dwB);

  // 6. dwB -> XT2 bf16 [pix][256]
  xpose<<<dim3(144, 4, 2), 256, 0, stream>>>(dwB, XT2);

  // 7. pointwise GEMM -> out (fp32 channel-major, 64x128 tiles)
  gemm_cf32<<<dim3(72, 4, 2), 256, 0, stream>>>(W7 + 1792 * 256, XT2, out);
}